// Round 7
// baseline (3100.142 us; speedup 1.0000x reference)
//
#include <hip/hip_runtime.h>
#include <hip/hip_bf16.h>
#include <math.h>

using u16 = unsigned short;
typedef __attribute__((ext_vector_type(8))) short short8;
typedef __attribute__((ext_vector_type(8))) _Float16 half8;
typedef __attribute__((ext_vector_type(4))) float f32x4;
typedef __attribute__((ext_vector_type(4))) u16 u16x4;

__device__ __constant__ int c_OFF[9] = {0, 119, 123, 135, 147, 157, 163, 169, 171};

__device__ __forceinline__ float h2f(u16 u) {
    _Float16 h;
    __builtin_memcpy(&h, &u, 2);
    return (float)h;
}
__device__ __forceinline__ u16 f2h(float f) {
    _Float16 h = (_Float16)f;
    u16 u;
    __builtin_memcpy(&u, &h, 2);
    return u;
}
__device__ __forceinline__ float sigf(float x) { return 1.f / (1.f + expf(-x)); }

// ---------------- diagnostics ----------------
__global__ void k_diagf(float* out, int G, float val) {
    int i = blockIdx.x * 256 + threadIdx.x;
    if (i < G) out[i] = val;
}

// ---------------- zero helpers ----------------
__global__ void k_zero_f32(float* p, int n) {
    int i = blockIdx.x * 256 + threadIdx.x;
    if (i < n) p[i] = 0.f;
}
__global__ void k_zero_u16(u16* p, int n) {
    int i = blockIdx.x * 256 + threadIdx.x;
    if (i < n) p[i] = 0;
}
__global__ void k_zero_int(int* p, int n) {
    int i = blockIdx.x * 256 + threadIdx.x;
    if (i < n) p[i] = 0;
}

// ---------------- fp32 -> fp16 convert ----------------
__global__ void k_cvtW(const float* __restrict__ src, u16* __restrict__ dst, int n) {
    int i = blockIdx.x * 256 + threadIdx.x;
    if (i < n) dst[i] = f2h(src[i]);
}

// ---------------- atom encoder ----------------
__global__ void k_embed(const int* __restrict__ x, const float* __restrict__ emb,
                        u16* __restrict__ out, int N) {
    __shared__ int rows[9];
    int n = blockIdx.x;
    int d = threadIdx.x;
    if (d < 9) rows[d] = x[n * 9 + d] + c_OFF[d];
    __syncthreads();
    float s = 0.f;
#pragma unroll
    for (int c = 0; c < 9; ++c) s += emb[rows[c] * 256 + d];
    out[(size_t)n * 256 + d] = f2h(s);
}

// ---------------- CSR build (in-place in rp) ----------------
__global__ void k_count(const int* __restrict__ tgt, int* rp, int E) {
    int e = blockIdx.x * 256 + threadIdx.x;
    if (e < E) atomicAdd(&rp[tgt[e]], 1);
}

__global__ void k_scan1(int* __restrict__ rp, int* __restrict__ bsum, int N) {
    int t = threadIdx.x;
    int base = blockIdx.x * 1024 + t * 4;
    int v0 = 0, v1 = 0, v2 = 0, v3 = 0;
    if (base + 3 < N) {
        v0 = rp[base]; v1 = rp[base + 1]; v2 = rp[base + 2]; v3 = rp[base + 3];
    } else {
        if (base < N) v0 = rp[base];
        if (base + 1 < N) v1 = rp[base + 1];
        if (base + 2 < N) v2 = rp[base + 2];
    }
    int s = v0 + v1 + v2 + v3;
    int lane = t & 63, w = t >> 6;
    int x = s;
    for (int o = 1; o < 64; o <<= 1) {
        int y = __shfl_up(x, o, 64);
        if (lane >= o) x += y;
    }
    __shared__ int wsum[4];
    if (lane == 63) wsum[w] = x;
    __syncthreads();
    int woff = 0;
    for (int i = 0; i < w; ++i) woff += wsum[i];
    int excl = woff + x - s;
    if (base < N) rp[base] = excl;
    if (base + 1 < N) rp[base + 1] = excl + v0;
    if (base + 2 < N) rp[base + 2] = excl + v0 + v1;
    if (base + 3 < N) rp[base + 3] = excl + v0 + v1 + v2;
    if (t == 255) bsum[blockIdx.x] = wsum[0] + wsum[1] + wsum[2] + wsum[3];
}

__global__ void k_scan2(int* bsum, int nb) {
    int t = threadIdx.x;
    int s = (t < nb) ? bsum[t] : 0;
    int lane = t & 63, w = t >> 6;
    int x = s;
    for (int o = 1; o < 64; o <<= 1) {
        int y = __shfl_up(x, o, 64);
        if (lane >= o) x += y;
    }
    __shared__ int wsum[4];
    if (lane == 63) wsum[w] = x;
    __syncthreads();
    int woff = 0;
    for (int i = 0; i < w; ++i) woff += wsum[i];
    if (t < nb) bsum[t] = woff + x - s;
}

__global__ void k_scan3(int* __restrict__ rp, const int* __restrict__ bsum, int N) {
    int i = blockIdx.x * 256 + threadIdx.x;
    if (i < N) rp[i] += bsum[i >> 10];
}

__global__ void k_fill(const int* __restrict__ src, const int* __restrict__ tgt,
                       int* __restrict__ rp, int* __restrict__ esrc, int E) {
    int e = blockIdx.x * 256 + threadIdx.x;
    if (e < E) {
        int t = tgt[e];
        int p = atomicAdd(&rp[t], 1);
        esrc[p] = src[e];
    }
}

// ---------------- GEMM: OUT[64 rows] <- Xin[64 rows] @ Wp^T (+cvec); OUT may equal Xin ----------------
__global__ __launch_bounds__(256, 2) void k_gemm(const u16* __restrict__ Xin,
                                                 const u16* __restrict__ W,
                                                 const float* __restrict__ cvec,
                                                 u16* __restrict__ out, int N) {
    __shared__ u16 As[64][264];
    __shared__ u16 Ws[256][40];
    int r0 = blockIdx.x * 64;
    int tid = threadIdx.x, lane = tid & 63, w = tid >> 6;
#pragma unroll
    for (int i = 0; i < 8; ++i) {
        int chunk = i * 256 + tid;
        int r = chunk >> 5, c8 = chunk & 31;
        *(short8*)&As[r][c8 * 8] = *(const short8*)&Xin[(size_t)(r0 + r) * 256 + c8 * 8];
    }
    f32x4 acc[16];
#pragma unroll
    for (int o = 0; o < 16; ++o) acc[o] = f32x4{0.f, 0.f, 0.f, 0.f};
    for (int k0 = 0; k0 < 256; k0 += 32) {
        __syncthreads();  // covers As staging (iter 0) and prior Ws readers
#pragma unroll
        for (int i = 0; i < 4; ++i) {
            int chunk = i * 256 + tid;
            int r = chunk >> 2, c8 = chunk & 3;
            *(short8*)&Ws[r][c8 * 8] = *(const short8*)&W[(size_t)r * 256 + k0 + c8 * 8];
        }
        __syncthreads();
        half8 af = *(const half8*)&As[w * 16 + (lane & 15)][k0 + (lane >> 4) * 8];
#pragma unroll
        for (int o = 0; o < 16; ++o) {
            half8 wf = *(const half8*)&Ws[o * 16 + (lane & 15)][(lane >> 4) * 8];
            acc[o] = __builtin_amdgcn_mfma_f32_16x16x32_f16(af, wf, acc[o], 0, 0, 0);
        }
    }
    // epilogue: stage output tile in LDS (reuse As), then coalesced row writes
    __syncthreads();
#pragma unroll
    for (int o = 0; o < 16; ++o) {
        int col = o * 16 + (lane & 15);
        float cv = cvec ? cvec[col] : 0.f;
#pragma unroll
        for (int r = 0; r < 4; ++r) {
            int row = w * 16 + (lane >> 4) * 4 + r;
            As[row][col] = f2h(acc[o][r] + cv);
        }
    }
    __syncthreads();
#pragma unroll
    for (int i = 0; i < 8; ++i) {
        int chunk = i * 256 + tid;
        int r = chunk >> 5, c8 = chunk & 31;
        *(short8*)&out[(size_t)(r0 + r) * 256 + c8 * 8] = *(const short8*)&As[r][c8 * 8];
    }
}

// ---------------- full-width aggregation: X <- D^-1/2 (A+I) D^-1/2 hw + bias (DB path) ----------------
template <bool RS>
__global__ __launch_bounds__(256) void k_agg(const u16* __restrict__ hw,
                                             const int* __restrict__ rp,
                                             const int* __restrict__ esrc,
                                             const float* __restrict__ bias,
                                             u16* __restrict__ X,
                                             float* __restrict__ stats, int N) {
    int lane = threadIdx.x & 63;
    int gw = blockIdx.x * 4 + (threadIdx.x >> 6);
    int nw = gridDim.x * 4;
    float bv[4];
#pragma unroll
    for (int j = 0; j < 4; ++j) bv[j] = bias[lane * 4 + j];
    float ss[4] = {0, 0, 0, 0}, qq[4] = {0, 0, 0, 0};
    for (int n = gw; n < N; n += nw) {
        int end = rp[n];
        int start = n ? rp[n - 1] : 0;
        float dn = rsqrtf((float)(end - start) + 1.f);
        u16x4 hv = *(const u16x4*)&hw[(size_t)n * 256 + lane * 4];
        float a[4];
#pragma unroll
        for (int j = 0; j < 4; ++j) a[j] = h2f(hv[j]) * dn * dn + bv[j];
        for (int j = start; j < end; ++j) {
            int s = esrc[j];
            int e2 = rp[s];
            int s2 = s ? rp[s - 1] : 0;
            float nr = rsqrtf((float)(e2 - s2) + 1.f) * dn;
            u16x4 v = *(const u16x4*)&hw[(size_t)s * 256 + lane * 4];
#pragma unroll
            for (int jj = 0; jj < 4; ++jj) a[jj] += h2f(v[jj]) * nr;
        }
        u16x4 o;
#pragma unroll
        for (int j = 0; j < 4; ++j) {
            if (RS) {
                a[j] = fmaxf(a[j], 0.f);
                ss[j] += a[j];
                qq[j] += a[j] * a[j];
            }
            o[j] = f2h(a[j]);
        }
        *(u16x4*)&X[(size_t)n * 256 + lane * 4] = o;
    }
    if (RS) {
        __shared__ float sh[512];
        int t = threadIdx.x;
        sh[t] = 0.f;
        sh[t + 256] = 0.f;
        __syncthreads();
#pragma unroll
        for (int j = 0; j < 4; ++j) {
            atomicAdd(&sh[lane * 4 + j], ss[j]);
            atomicAdd(&sh[256 + lane * 4 + j], qq[j]);
        }
        __syncthreads();
        atomicAdd(&stats[t], sh[t]);
        atomicAdd(&stats[t + 256], sh[t + 256]);
    }
}

// ---------------- Q-path: snapshot + quarter aggregation (fallback) ----------------
__global__ void k_copycol(const u16* __restrict__ X, u16* __restrict__ Q, int q, int N) {
    int i = blockIdx.x * 256 + threadIdx.x;
    if (i >= N * 16) return;
    int n = i >> 4, c4 = (i & 15) * 4;
    *(u16x4*)&Q[(size_t)n * 64 + c4] = *(const u16x4*)&X[(size_t)n * 256 + q * 64 + c4];
}

template <bool RS>
__global__ __launch_bounds__(256) void k_aggq(const u16* __restrict__ Q,
                                              const int* __restrict__ rp,
                                              const int* __restrict__ esrc,
                                              const float* __restrict__ bias,
                                              u16* __restrict__ X,
                                              float* __restrict__ stats, int q, int N) {
    int lane = threadIdx.x & 63;
    int gw = blockIdx.x * 4 + (threadIdx.x >> 6);
    int nw = gridDim.x * 4;
    int col = q * 64 + lane;
    float bv = bias[col];
    float ss = 0.f, qq = 0.f;
    for (int n = gw; n < N; n += nw) {
        int end = rp[n];
        int start = n ? rp[n - 1] : 0;
        float dn = rsqrtf((float)(end - start) + 1.f);
        float a = h2f(Q[(size_t)n * 64 + lane]) * dn * dn + bv;
        for (int j = start; j < end; ++j) {
            int s = esrc[j];
            int e2 = rp[s];
            int s2 = s ? rp[s - 1] : 0;
            float ds = rsqrtf((float)(e2 - s2) + 1.f);
            a += h2f(Q[(size_t)s * 64 + lane]) * ds * dn;
        }
        if (RS) {
            a = fmaxf(a, 0.f);
            ss += a;
            qq += a * a;
        }
        X[(size_t)n * 256 + col] = f2h(a);
    }
    if (RS) {
        __shared__ float sh[128];
        int t = threadIdx.x;
        if (t < 128) sh[t] = 0.f;
        __syncthreads();
        atomicAdd(&sh[lane], ss);
        atomicAdd(&sh[64 + lane], qq);
        __syncthreads();
        if (t < 64) {
            atomicAdd(&stats[col], sh[lane]);
            atomicAdd(&stats[256 + col], sh[64 + lane]);
        }
    }
}

__global__ void k_bnparam(const float* __restrict__ stats, const float* __restrict__ gamma,
                          const float* __restrict__ beta, float* __restrict__ st, int N) {
    int d = threadIdx.x;
    float inv = 1.f / (float)N;
    float mu = stats[d] * inv;
    float var = fmaxf(stats[256 + d] * inv - mu * mu, 0.f);
    float sc = gamma[d] * rsqrtf(var + 1e-5f);
    st[d] = sc;
    st[256 + d] = beta[d] - mu * sc;
}

__global__ void k_fold(const float* __restrict__ W, const float* __restrict__ st,
                       u16* __restrict__ Wp, float* __restrict__ cvec) {
    __shared__ float red[256];
    int o = blockIdx.x, k = threadIdx.x;
    float w = W[o * 256 + k];
    Wp[o * 256 + k] = f2h(w * st[k]);
    red[k] = w * st[256 + k];
    __syncthreads();
    for (int s = 128; s > 0; s >>= 1) {
        if (k < s) red[k] += red[k + s];
        __syncthreads();
    }
    if (k == 0) cvec[o] = red[0];
}

// ---------------- set2set GEMM: C[M,O](f32) = A[M,K](fp16) @ W[O,K](fp16)^T + cvec ----------------
__global__ __launch_bounds__(256, 2) void k_gemmf(const u16* __restrict__ A,
                                                  const u16* __restrict__ W,
                                                  const float* __restrict__ cvec,
                                                  float* __restrict__ C, int M, int K, int O) {
    const int PAD = 8;
    __shared__ u16 As[128][64 + PAD];
    __shared__ u16 Ws[128][64 + PAD];
    int tM = blockIdx.x, tO = blockIdx.y;
    int tid = threadIdx.x;
    int lane = tid & 63, wid = tid >> 6;
    int wM = wid & 1, wO = wid >> 1;
    f32x4 acc[4][4] = {};
    size_t rowA0 = (size_t)tM * 128, rowW0 = (size_t)tO * 128;
    for (int k0 = 0; k0 < K; k0 += 64) {
#pragma unroll
        for (int i = 0; i < 4; ++i) {
            int chunk = tid + i * 256;
            int r = chunk >> 3, c16 = chunk & 7;
            *(short8*)&As[r][c16 * 8] = *(const short8*)&A[(rowA0 + r) * K + k0 + c16 * 8];
            *(short8*)&Ws[r][c16 * 8] = *(const short8*)&W[(rowW0 + r) * K + k0 + c16 * 8];
        }
        __syncthreads();
#pragma unroll
        for (int ks = 0; ks < 2; ++ks) {
            half8 af[4], wf[4];
#pragma unroll
            for (int m = 0; m < 4; ++m)
                af[m] = *(const half8*)&As[wM * 64 + m * 16 + (lane & 15)][ks * 32 + (lane >> 4) * 8];
#pragma unroll
            for (int o = 0; o < 4; ++o)
                wf[o] = *(const half8*)&Ws[wO * 64 + o * 16 + (lane & 15)][ks * 32 + (lane >> 4) * 8];
#pragma unroll
            for (int m = 0; m < 4; ++m)
#pragma unroll
                for (int o = 0; o < 4; ++o)
                    acc[m][o] = __builtin_amdgcn_mfma_f32_16x16x32_f16(af[m], wf[o], acc[m][o], 0, 0, 0);
        }
        __syncthreads();
    }
#pragma unroll
    for (int m = 0; m < 4; ++m) {
        int R0 = tM * 128 + wM * 64 + m * 16 + (lane >> 4) * 4;
#pragma unroll
        for (int o = 0; o < 4; ++o) {
            int Cc = tO * 128 + wO * 64 + o * 16 + (lane & 15);
            float cv = cvec[Cc];
#pragma unroll
            for (int r = 0; r < 4; ++r)
                C[(size_t)(R0 + r) * O + Cc] = acc[m][o][r] + cv;
        }
    }
}

// ---------------- set2set pieces ----------------
__global__ void k_wcat(const float* __restrict__ Wi, const float* __restrict__ Wh,
                       const float* __restrict__ bi, const float* __restrict__ bh,
                       u16* __restrict__ Wcat, float* __restrict__ bcat) {
    int o = blockIdx.x;
    int t = threadIdx.x;
    for (int c = t; c < 512; c += 256) Wcat[(size_t)o * 768 + c] = f2h(Wi[(size_t)o * 512 + c]);
    if (t < 256) Wcat[(size_t)o * 768 + 512 + t] = f2h(Wh[(size_t)o * 256 + t]);
    if (t == 0) bcat[o] = bi[o] + bh[o];
}

__global__ void k_lstm(const float* __restrict__ gates, float* __restrict__ cs,
                       float* __restrict__ hsb, u16* __restrict__ qsh, int G) {
    int idx = blockIdx.x * 256 + threadIdx.x;
    if (idx >= G * 256) return;
    int g = idx >> 8, d = idx & 255;
    const float* gt = &gates[(size_t)g * 1024];
    float gi = gt[d], gf = gt[256 + d], gg = gt[512 + d], go = gt[768 + d];
    float c = sigf(gf) * cs[idx] + sigf(gi) * tanhf(gg);
    float hh = sigf(go) * tanhf(c);
    cs[idx] = c;
    hsb[idx] = hh;
    u16 hb = f2h(hh);
    qsh[(size_t)g * 768 + d] = hb;
    qsh[(size_t)g * 768 + 512 + d] = hb;
}

// attn with LDS staging: chunk of 128 nodes lives in LDS between pass1 and pass2
__global__ __launch_bounds__(256) void k_attn(const u16* __restrict__ h3,
                                              const float* __restrict__ hs,
                                              const int* __restrict__ batch,
                                              u16* __restrict__ qsh, int N, int G) {
    int g = blockIdx.x;
    int tid = threadIdx.x, lane = tid & 63, wid = tid >> 6;
    int lo = 0, hi = N;
    while (lo < hi) {
        int mid = (lo + hi) >> 1;
        if (batch[mid] < g) lo = mid + 1; else hi = mid;
    }
    int start = lo;
    hi = N;
    while (lo < hi) {
        int mid = (lo + hi) >> 1;
        if (batch[mid] < g + 1) lo = mid + 1; else hi = mid;
    }
    int end = lo;
    int cnt = end - start;

    __shared__ u16 stage[128][256];
    __shared__ float earr[128];
    __shared__ float red[256];

    float q0 = hs[(size_t)g * 256 + lane * 4 + 0];
    float q1 = hs[(size_t)g * 256 + lane * 4 + 1];
    float q2 = hs[(size_t)g * 256 + lane * 4 + 2];
    float q3 = hs[(size_t)g * 256 + lane * 4 + 3];

    float m = -INFINITY, z = 0.f, racc = 0.f;
    for (int c0 = start; c0 < end; c0 += 128) {
        int cn = min(128, end - c0);
        // pass1: dot + stage into LDS (one global read of the chunk)
        for (int i = wid; i < cn; i += 4) {
            u16x4 hv = *(const u16x4*)&h3[(size_t)(c0 + i) * 256 + lane * 4];
            *(u16x4*)&stage[i][lane * 4] = hv;
            float e = h2f(hv[0]) * q0 + h2f(hv[1]) * q1 + h2f(hv[2]) * q2 + h2f(hv[3]) * q3;
            for (int off = 32; off; off >>= 1) e += __shfl_xor(e, off, 64);
            if (lane == 0) earr[i] = e;
        }
        __syncthreads();
        float lm = -INFINITY;
        for (int i = tid; i < cn; i += 256) lm = fmaxf(lm, earr[i]);
        red[tid] = lm;
        __syncthreads();
        for (int s = 128; s > 0; s >>= 1) {
            if (tid < s) red[tid] = fmaxf(red[tid], red[tid + s]);
            __syncthreads();
        }
        float mnew = fmaxf(m, red[0]);
        __syncthreads();
        float rf = (m == -INFINITY) ? 0.f : expf(m - mnew);
        float lz = 0.f;
        for (int i = tid; i < cn; i += 256) {
            float ee = expf(earr[i] - mnew);
            earr[i] = ee;
            lz += ee;
        }
        red[tid] = lz;
        __syncthreads();
        for (int s = 128; s > 0; s >>= 1) {
            if (tid < s) red[tid] += red[tid + s];
            __syncthreads();
        }
        z = z * rf + red[0];
        __syncthreads();
        // pass2 from LDS: thread = column
        racc *= rf;
        for (int i = 0; i < cn; ++i)
            racc += earr[i] * h2f(stage[i][tid]);
        m = mnew;
        __syncthreads();
    }
    float r = (cnt > 0) ? racc / fmaxf(z, 1e-30f) : 0.f;
    qsh[(size_t)g * 768 + 256 + tid] = f2h(r);
}

// lin1/lin2 compose: weff[c] = sum_t l2W[t]*l1W[t][c]; weff[512] = l2W.l1b + l2b
__global__ void k_wfold(const float* __restrict__ l1W, const float* __restrict__ l1b,
                        const float* __restrict__ l2W, const float* __restrict__ l2b,
                        float* __restrict__ weff) {
    int c = blockIdx.x * 256 + threadIdx.x;
    if (c < 512) {
        float s = 0.f;
        for (int t = 0; t < 128; ++t) s += l2W[t] * l1W[(size_t)t * 512 + c];
        weff[c] = s;
    }
    if (c == 0) {
        float b = l2b[0];
        for (int t = 0; t < 128; ++t) b += l2W[t] * l1b[t];
        weff[512] = b;
    }
}

// out[g] = sigmoid(weff . qstar[g] + beff) — one wave per graph
__global__ __launch_bounds__(256) void k_final2(const u16* __restrict__ qsh,
                                                const float* __restrict__ weff,
                                                float* __restrict__ out, int G) {
    __shared__ float wsm[513];
    int tid = threadIdx.x;
    for (int j = tid; j < 513; j += 256) wsm[j] = weff[j];
    __syncthreads();
    int g = blockIdx.x * 4 + (tid >> 6);
    int lane = tid & 63;
    if (g >= G) return;
    const u16* qp = &qsh[(size_t)g * 768];
    float s = 0.f;
#pragma unroll
    for (int j = 0; j < 8; ++j) s += h2f(qp[lane * 8 + j]) * wsm[lane * 8 + j];
    for (int off = 32; off; off >>= 1) s += __shfl_xor(s, off, 64);
    if (lane == 0) out[g] = sigf(s + wsm[512]);
}

// ---------------- host ----------------
extern "C" void kernel_launch(void* const* d_in, const int* in_sizes, int n_in,
                              void* d_out, int out_size, void* d_ws, size_t ws_size,
                              hipStream_t stream) {
    const int* x = (const int*)d_in[0];
    const int* ei = (const int*)d_in[1];
    const int* batch = (const int*)d_in[2];
    const float* atom_emb = (const float*)d_in[4];
    const float* W1 = (const float*)d_in[5];
    const float* b1 = (const float*)d_in[6];
    const float* W2 = (const float*)d_in[7];
    const float* b2 = (const float*)d_in[8];
    const float* W3 = (const float*)d_in[9];
    const float* b3 = (const float*)d_in[10];
    const float* gamma = (const float*)d_in[11];
    const float* beta = (const float*)d_in[12];
    const float* Wi = (const float*)d_in[13];
    const float* Wh = (const float*)d_in[14];
    const float* bi = (const float*)d_in[15];
    const float* bh = (const float*)d_in[16];
    const float* l1W = (const float*)d_in[17];
    const float* l1b = (const float*)d_in[18];
    const float* l2W = (const float*)d_in[19];
    const float* l2b = (const float*)d_in[20];

    const int N = in_sizes[0] / 9;
    const int E = in_sizes[1] / 2;
    const int G = out_size;
    const int* srcp = ei;
    const int* tgtp = ei + E;

    char* ws = (char*)d_ws;
    size_t off = 0;
    auto alloc = [&](size_t bytes) -> void* {
        void* p = ws + off;
        off += (bytes + 255) & ~(size_t)255;
        return p;
    };
    u16* X = (u16*)alloc((size_t)N * 256 * 2);  // 128 MiB
    int* rp = (int*)alloc((size_t)N * 4);
    int* esrc = (int*)alloc((size_t)E * 4);
    float* stats = (float*)alloc(512 * 4);
    float* stbuf = (float*)alloc(512 * 4);
    float* cvec = (float*)alloc(256 * 4);
    u16* Wp = (u16*)alloc(256 * 256 * 2);
    int* bsum = (int*)alloc(1024 * 4);
    float* weff = (float*)alloc(513 * 4);
    size_t offR = off;

    // region R, set2set view (aliases Y in DB mode / Q in fallback mode)
    size_t o2 = offR;
    auto alloc2 = [&](size_t bytes) -> void* {
        void* p = ws + o2;
        o2 += (bytes + 255) & ~(size_t)255;
        return p;
    };
    u16* Wcat = (u16*)alloc2((size_t)1024 * 768 * 2);
    float* bcat = (float*)alloc2(1024 * 4);
    u16* qsh = (u16*)alloc2((size_t)G * 768 * 2);
    float* gates = (float*)alloc2((size_t)G * 1024 * 4);
    float* hsb = (float*)alloc2((size_t)G * 256 * 4);
    float* csb = (float*)alloc2((size_t)G * 256 * 4);
    size_t s2sR = o2 - offR;

    size_t bufBytes = ((size_t)N * 256 * 2 + 255) & ~(size_t)255;  // 128 MiB
    size_t qBytes = ((size_t)N * 64 * 2 + 255) & ~(size_t)255;     // 32 MiB
    size_t needDB = offR + (bufBytes > s2sR ? bufBytes : s2sR);
    size_t needQ = offR + (qBytes > s2sR ? qBytes : s2sR);
    bool useDB = ws_size >= needDB;
    if (!useDB && ws_size < needQ) {
        k_diagf<<<(G + 255) / 256, 256, 0, stream>>>((float*)d_out, G, 12345.0f);
        return;
    }
    u16* Y = (u16*)(ws + offR);  // DB: full buffer; Q path: quarter snapshot

    // embed + CSR
    k_embed<<<N, 256, 0, stream>>>(x, atom_emb, X, N);
    k_zero_int<<<(N + 255) / 256, 256, 0, stream>>>(rp, N);
    k_count<<<(E + 255) / 256, 256, 0, stream>>>(tgtp, rp, E);
    int nb1 = (N + 1023) / 1024;
    k_scan1<<<nb1, 256, 0, stream>>>(rp, bsum, N);
    k_scan2<<<1, 256, 0, stream>>>(bsum, nb1);
    k_scan3<<<(N + 255) / 256, 256, 0, stream>>>(rp, bsum, N);
    k_fill<<<(E + 255) / 256, 256, 0, stream>>>(srcp, tgtp, rp, esrc, E);

    int gipb = N / 64;
    int ccb = (N * 16 + 255) / 256;

    for (int conv = 0; conv < 3; ++conv) {
        const float* Wsrc = conv == 0 ? W1 : (conv == 1 ? W2 : W3);
        const float* bsrc = conv == 0 ? b1 : (conv == 1 ? b2 : b3);
        bool rs = conv < 2;
        if (conv == 0)
            k_cvtW<<<256, 256, 0, stream>>>(Wsrc, Wp, 65536);
        else
            k_fold<<<256, 256, 0, stream>>>(Wsrc, stbuf, Wp, cvec);
        if (rs) k_zero_f32<<<2, 256, 0, stream>>>(stats, 512);
        if (useDB) {
            k_gemm<<<gipb, 256, 0, stream>>>(X, Wp, conv ? cvec : nullptr, Y, N);
            if (rs)
                k_agg<true><<<1024, 256, 0, stream>>>(Y, rp, esrc, bsrc, X, stats, N);
            else
                k_agg<false><<<1024, 256, 0, stream>>>(Y, rp, esrc, bsrc, X, nullptr, N);
        } else {
            k_gemm<<<gipb, 256, 0, stream>>>(X, Wp, conv ? cvec : nullptr, X, N);
            for (int q = 0; q < 4; ++q) {
                k_copycol<<<ccb, 256, 0, stream>>>(X, Y, q, N);
                if (rs)
                    k_aggq<true><<<1024, 256, 0, stream>>>(Y, rp, esrc, bsrc, X, stats, q, N);
                else
                    k_aggq<false><<<1024, 256, 0, stream>>>(Y, rp, esrc, bsrc, X, nullptr, q, N);
            }
        }
        if (rs) k_bnparam<<<1, 256, 0, stream>>>(stats, gamma, beta, stbuf, N);
    }
    // h3 now in X

    // set2set
    k_wcat<<<1024, 256, 0, stream>>>(Wi, Wh, bi, bh, Wcat, bcat);
    k_zero_u16<<<(G * 768 + 255) / 256, 256, 0, stream>>>(qsh, G * 768);
    k_zero_f32<<<(G * 256 + 255) / 256, 256, 0, stream>>>(csb, G * 256);
    dim3 ggates(G / 128, 8);
    for (int s = 0; s < 4; ++s) {
        k_gemmf<<<ggates, 256, 0, stream>>>(qsh, Wcat, bcat, gates, G, 768, 1024);
        k_lstm<<<(G * 256 + 255) / 256, 256, 0, stream>>>(gates, csb, hsb, qsh, G);
        k_attn<<<G, 256, 0, stream>>>(X, hsb, batch, qsh, N, G);
    }
    k_wfold<<<2, 256, 0, stream>>>(l1W, l1b, l2W, l2b, weff);
    k_final2<<<(G + 3) / 4, 256, 0, stream>>>(qsh, weff, (float*)d_out, G);
}

// Round 8
// 2493.513 us; speedup vs baseline: 1.2433x; 1.2433x over previous
//
#include <hip/hip_runtime.h>
#include <hip/hip_bf16.h>
#include <math.h>

using u16 = unsigned short;
typedef __attribute__((ext_vector_type(8))) short short8;
typedef __attribute__((ext_vector_type(8))) _Float16 half8;
typedef __attribute__((ext_vector_type(4))) float f32x4;
typedef __attribute__((ext_vector_type(4))) u16 u16x4;

__device__ __constant__ int c_OFF[9] = {0, 119, 123, 135, 147, 157, 163, 169, 171};

__device__ __forceinline__ float h2f(u16 u) {
    _Float16 h;
    __builtin_memcpy(&h, &u, 2);
    return (float)h;
}
__device__ __forceinline__ u16 f2h(float f) {
    _Float16 h = (_Float16)f;
    u16 u;
    __builtin_memcpy(&u, &h, 2);
    return u;
}
__device__ __forceinline__ float sigf(float x) { return 1.f / (1.f + expf(-x)); }

// ---------------- diagnostics ----------------
__global__ void k_diagf(float* out, int G, float val) {
    int i = blockIdx.x * 256 + threadIdx.x;
    if (i < G) out[i] = val;
}

// ---------------- zero helpers ----------------
__global__ void k_zero_f32(float* p, int n) {
    int i = blockIdx.x * 256 + threadIdx.x;
    if (i < n) p[i] = 0.f;
}
__global__ void k_zero_u16(u16* p, int n) {
    int i = blockIdx.x * 256 + threadIdx.x;
    if (i < n) p[i] = 0;
}
__global__ void k_zero_int(int* p, int n) {
    int i = blockIdx.x * 256 + threadIdx.x;
    if (i < n) p[i] = 0;
}

// ---------------- fp32 -> fp16 convert ----------------
__global__ void k_cvtW(const float* __restrict__ src, u16* __restrict__ dst, int n) {
    int i = blockIdx.x * 256 + threadIdx.x;
    if (i < n) dst[i] = f2h(src[i]);
}

// ---------------- atom encoder ----------------
__global__ void k_embed(const int* __restrict__ x, const float* __restrict__ emb,
                        u16* __restrict__ out, int N) {
    __shared__ int rows[9];
    int n = blockIdx.x;
    int d = threadIdx.x;
    if (d < 9) rows[d] = x[n * 9 + d] + c_OFF[d];
    __syncthreads();
    float s = 0.f;
#pragma unroll
    for (int c = 0; c < 9; ++c) s += emb[rows[c] * 256 + d];
    out[(size_t)n * 256 + d] = f2h(s);
}

// ---------------- graph segment starts from sorted batch ----------------
__global__ void k_gstart(const int* __restrict__ batch, int* __restrict__ gstart, int N, int G) {
    int i = blockIdx.x * 256 + threadIdx.x;
    if (i >= N) return;
    int b = batch[i];
    if (i == 0) {
        for (int g = 0; g <= b; ++g) gstart[g] = 0;
    } else {
        int p = batch[i - 1];
        for (int g = p + 1; g <= b; ++g) gstart[g] = i;
    }
    if (i == N - 1) {
        for (int g = b + 1; g <= G; ++g) gstart[g] = N;
    }
}

// ---------------- CSR build (in-place in rp) ----------------
__global__ void k_count(const int* __restrict__ tgt, int* rp, int E) {
    int e = blockIdx.x * 256 + threadIdx.x;
    if (e < E) atomicAdd(&rp[tgt[e]], 1);
}

__global__ void k_dinv(const int* __restrict__ cnt, float* __restrict__ dinv, int N) {
    int i = blockIdx.x * 256 + threadIdx.x;
    if (i < N) dinv[i] = rsqrtf((float)cnt[i] + 1.f);
}

__global__ void k_scan1(int* __restrict__ rp, int* __restrict__ bsum, int N) {
    int t = threadIdx.x;
    int base = blockIdx.x * 1024 + t * 4;
    int v0 = 0, v1 = 0, v2 = 0, v3 = 0;
    if (base + 3 < N) {
        v0 = rp[base]; v1 = rp[base + 1]; v2 = rp[base + 2]; v3 = rp[base + 3];
    } else {
        if (base < N) v0 = rp[base];
        if (base + 1 < N) v1 = rp[base + 1];
        if (base + 2 < N) v2 = rp[base + 2];
    }
    int s = v0 + v1 + v2 + v3;
    int lane = t & 63, w = t >> 6;
    int x = s;
    for (int o = 1; o < 64; o <<= 1) {
        int y = __shfl_up(x, o, 64);
        if (lane >= o) x += y;
    }
    __shared__ int wsum[4];
    if (lane == 63) wsum[w] = x;
    __syncthreads();
    int woff = 0;
    for (int i = 0; i < w; ++i) woff += wsum[i];
    int excl = woff + x - s;
    if (base < N) rp[base] = excl;
    if (base + 1 < N) rp[base + 1] = excl + v0;
    if (base + 2 < N) rp[base + 2] = excl + v0 + v1;
    if (base + 3 < N) rp[base + 3] = excl + v0 + v1 + v2;
    if (t == 255) bsum[blockIdx.x] = wsum[0] + wsum[1] + wsum[2] + wsum[3];
}

__global__ void k_scan2(int* bsum, int nb) {
    int t = threadIdx.x;
    int s = (t < nb) ? bsum[t] : 0;
    int lane = t & 63, w = t >> 6;
    int x = s;
    for (int o = 1; o < 64; o <<= 1) {
        int y = __shfl_up(x, o, 64);
        if (lane >= o) x += y;
    }
    __shared__ int wsum[4];
    if (lane == 63) wsum[w] = x;
    __syncthreads();
    int woff = 0;
    for (int i = 0; i < w; ++i) woff += wsum[i];
    if (t < nb) bsum[t] = woff + x - s;
}

__global__ void k_scan3(int* __restrict__ rp, const int* __restrict__ bsum, int N) {
    int i = blockIdx.x * 256 + threadIdx.x;
    if (i < N) rp[i] += bsum[i >> 10];
}

// fill with per-edge norm; afterwards rp[n] = end(n), start(n) = rp[n-1]
__global__ void k_fill(const int* __restrict__ src, const int* __restrict__ tgt,
                       int* __restrict__ rp, const float* __restrict__ dinv,
                       int* __restrict__ esrc, float* __restrict__ enorm, int E) {
    int e = blockIdx.x * 256 + threadIdx.x;
    if (e < E) {
        int t = tgt[e];
        int s = src[e];
        int p = atomicAdd(&rp[t], 1);
        esrc[p] = s;
        enorm[p] = dinv[s] * dinv[t];
    }
}

// ---------------- GEMM: OUT[64 rows] <- Xin[64 rows] @ Wp^T (+cvec); OUT may equal Xin ----------------
__global__ __launch_bounds__(256, 2) void k_gemm(const u16* __restrict__ Xin,
                                                 const u16* __restrict__ W,
                                                 const float* __restrict__ cvec,
                                                 u16* __restrict__ out, int N) {
    __shared__ u16 As[64][264];
    __shared__ u16 Ws[256][40];
    int r0 = blockIdx.x * 64;
    int tid = threadIdx.x, lane = tid & 63, w = tid >> 6;
#pragma unroll
    for (int i = 0; i < 8; ++i) {
        int chunk = i * 256 + tid;
        int r = chunk >> 5, c8 = chunk & 31;
        *(short8*)&As[r][c8 * 8] = *(const short8*)&Xin[(size_t)(r0 + r) * 256 + c8 * 8];
    }
    f32x4 acc[16];
#pragma unroll
    for (int o = 0; o < 16; ++o) acc[o] = f32x4{0.f, 0.f, 0.f, 0.f};
    for (int k0 = 0; k0 < 256; k0 += 32) {
        __syncthreads();
#pragma unroll
        for (int i = 0; i < 4; ++i) {
            int chunk = i * 256 + tid;
            int r = chunk >> 2, c8 = chunk & 3;
            *(short8*)&Ws[r][c8 * 8] = *(const short8*)&W[(size_t)r * 256 + k0 + c8 * 8];
        }
        __syncthreads();
        half8 af = *(const half8*)&As[w * 16 + (lane & 15)][k0 + (lane >> 4) * 8];
#pragma unroll
        for (int o = 0; o < 16; ++o) {
            half8 wf = *(const half8*)&Ws[o * 16 + (lane & 15)][(lane >> 4) * 8];
            acc[o] = __builtin_amdgcn_mfma_f32_16x16x32_f16(af, wf, acc[o], 0, 0, 0);
        }
    }
    __syncthreads();
#pragma unroll
    for (int o = 0; o < 16; ++o) {
        int col = o * 16 + (lane & 15);
        float cv = cvec ? cvec[col] : 0.f;
#pragma unroll
        for (int r = 0; r < 4; ++r) {
            int row = w * 16 + (lane >> 4) * 4 + r;
            As[row][col] = f2h(acc[o][r] + cv);
        }
    }
    __syncthreads();
#pragma unroll
    for (int i = 0; i < 8; ++i) {
        int chunk = i * 256 + tid;
        int r = chunk >> 5, c8 = chunk & 31;
        *(short8*)&out[(size_t)(r0 + r) * 256 + c8 * 8] = *(const short8*)&As[r][c8 * 8];
    }
}

// ---------------- full-width aggregation (DB path) ----------------
template <bool RS>
__global__ __launch_bounds__(256) void k_agg(const u16* __restrict__ hw,
                                             const int* __restrict__ rp,
                                             const int* __restrict__ esrc,
                                             const float* __restrict__ enorm,
                                             const float* __restrict__ dinv,
                                             const float* __restrict__ bias,
                                             u16* __restrict__ X,
                                             float* __restrict__ stats, int N) {
    int lane = threadIdx.x & 63;
    int gw = blockIdx.x * 4 + (threadIdx.x >> 6);
    int nw = gridDim.x * 4;
    float bv[4];
#pragma unroll
    for (int j = 0; j < 4; ++j) bv[j] = bias[lane * 4 + j];
    float ss[4] = {0, 0, 0, 0}, qq[4] = {0, 0, 0, 0};
    for (int n = gw; n < N; n += nw) {
        int end = rp[n];
        int start = n ? rp[n - 1] : 0;
        float dn = dinv[n];
        u16x4 hv = *(const u16x4*)&hw[(size_t)n * 256 + lane * 4];
        float a[4];
#pragma unroll
        for (int j = 0; j < 4; ++j) a[j] = h2f(hv[j]) * dn * dn + bv[j];
        for (int j = start; j < end; ++j) {
            int s = esrc[j];
            float nr = enorm[j];
            u16x4 v = *(const u16x4*)&hw[(size_t)s * 256 + lane * 4];
#pragma unroll
            for (int jj = 0; jj < 4; ++jj) a[jj] += h2f(v[jj]) * nr;
        }
        u16x4 o;
#pragma unroll
        for (int j = 0; j < 4; ++j) {
            if (RS) {
                a[j] = fmaxf(a[j], 0.f);
                ss[j] += a[j];
                qq[j] += a[j] * a[j];
            }
            o[j] = f2h(a[j]);
        }
        *(u16x4*)&X[(size_t)n * 256 + lane * 4] = o;
    }
    if (RS) {
        __shared__ float sh[512];
        int t = threadIdx.x;
        sh[t] = 0.f;
        sh[t + 256] = 0.f;
        __syncthreads();
#pragma unroll
        for (int j = 0; j < 4; ++j) {
            atomicAdd(&sh[lane * 4 + j], ss[j]);
            atomicAdd(&sh[256 + lane * 4 + j], qq[j]);
        }
        __syncthreads();
        atomicAdd(&stats[t], sh[t]);
        atomicAdd(&stats[t + 256], sh[t + 256]);
    }
}

// ---------------- Q-path: snapshot + quarter aggregation (fallback) ----------------
__global__ void k_copycol(const u16* __restrict__ X, u16* __restrict__ Q, int q, int N) {
    int i = blockIdx.x * 256 + threadIdx.x;
    if (i >= N * 16) return;
    int n = i >> 4, c4 = (i & 15) * 4;
    *(u16x4*)&Q[(size_t)n * 64 + c4] = *(const u16x4*)&X[(size_t)n * 256 + q * 64 + c4];
}

template <bool RS>
__global__ __launch_bounds__(256) void k_aggq(const u16* __restrict__ Q,
                                              const int* __restrict__ rp,
                                              const int* __restrict__ esrc,
                                              const float* __restrict__ enorm,
                                              const float* __restrict__ dinv,
                                              const float* __restrict__ bias,
                                              u16* __restrict__ X,
                                              float* __restrict__ stats, int q, int N) {
    int lane = threadIdx.x & 63;
    int gw = blockIdx.x * 4 + (threadIdx.x >> 6);
    int nw = gridDim.x * 4;
    int col = q * 64 + lane;
    float bv = bias[col];
    float ss = 0.f, qq = 0.f;
    for (int n = gw; n < N; n += nw) {
        int end = rp[n];
        int start = n ? rp[n - 1] : 0;
        float dn = dinv[n];
        float a = h2f(Q[(size_t)n * 64 + lane]) * dn * dn + bv;
        for (int j = start; j < end; ++j) {
            int s = esrc[j];
            a += h2f(Q[(size_t)s * 64 + lane]) * enorm[j];
        }
        if (RS) {
            a = fmaxf(a, 0.f);
            ss += a;
            qq += a * a;
        }
        X[(size_t)n * 256 + col] = f2h(a);
    }
    if (RS) {
        __shared__ float sh[128];
        int t = threadIdx.x;
        if (t < 128) sh[t] = 0.f;
        __syncthreads();
        atomicAdd(&sh[lane], ss);
        atomicAdd(&sh[64 + lane], qq);
        __syncthreads();
        if (t < 64) {
            atomicAdd(&stats[col], sh[lane]);
            atomicAdd(&stats[256 + col], sh[64 + lane]);
        }
    }
}

__global__ void k_bnparam(const float* __restrict__ stats, const float* __restrict__ gamma,
                          const float* __restrict__ beta, float* __restrict__ st, int N) {
    int d = threadIdx.x;
    float inv = 1.f / (float)N;
    float mu = stats[d] * inv;
    float var = fmaxf(stats[256 + d] * inv - mu * mu, 0.f);
    float sc = gamma[d] * rsqrtf(var + 1e-5f);
    st[d] = sc;
    st[256 + d] = beta[d] - mu * sc;
}

__global__ void k_fold(const float* __restrict__ W, const float* __restrict__ st,
                       u16* __restrict__ Wp, float* __restrict__ cvec) {
    __shared__ float red[256];
    int o = blockIdx.x, k = threadIdx.x;
    float w = W[o * 256 + k];
    Wp[o * 256 + k] = f2h(w * st[k]);
    red[k] = w * st[256 + k];
    __syncthreads();
    for (int s = 128; s > 0; s >>= 1) {
        if (k < s) red[k] += red[k + s];
        __syncthreads();
    }
    if (k == 0) cvec[o] = red[0];
}

// ---------------- set2set GEMM: C[M,O](f32) = A[M,K](fp16) @ W[O,K](fp16)^T + cvec ----------------
__global__ __launch_bounds__(256, 2) void k_gemmf(const u16* __restrict__ A,
                                                  const u16* __restrict__ W,
                                                  const float* __restrict__ cvec,
                                                  float* __restrict__ C, int M, int K, int O) {
    const int PAD = 8;
    __shared__ u16 As[128][64 + PAD];
    __shared__ u16 Ws[128][64 + PAD];
    int tM = blockIdx.x, tO = blockIdx.y;
    int tid = threadIdx.x;
    int lane = tid & 63, wid = tid >> 6;
    int wM = wid & 1, wO = wid >> 1;
    f32x4 acc[4][4] = {};
    size_t rowA0 = (size_t)tM * 128, rowW0 = (size_t)tO * 128;
    for (int k0 = 0; k0 < K; k0 += 64) {
#pragma unroll
        for (int i = 0; i < 4; ++i) {
            int chunk = tid + i * 256;
            int r = chunk >> 3, c16 = chunk & 7;
            *(short8*)&As[r][c16 * 8] = *(const short8*)&A[(rowA0 + r) * K + k0 + c16 * 8];
            *(short8*)&Ws[r][c16 * 8] = *(const short8*)&W[(rowW0 + r) * K + k0 + c16 * 8];
        }
        __syncthreads();
#pragma unroll
        for (int ks = 0; ks < 2; ++ks) {
            half8 af[4], wf[4];
#pragma unroll
            for (int m = 0; m < 4; ++m)
                af[m] = *(const half8*)&As[wM * 64 + m * 16 + (lane & 15)][ks * 32 + (lane >> 4) * 8];
#pragma unroll
            for (int o = 0; o < 4; ++o)
                wf[o] = *(const half8*)&Ws[wO * 64 + o * 16 + (lane & 15)][ks * 32 + (lane >> 4) * 8];
#pragma unroll
            for (int m = 0; m < 4; ++m)
#pragma unroll
                for (int o = 0; o < 4; ++o)
                    acc[m][o] = __builtin_amdgcn_mfma_f32_16x16x32_f16(af[m], wf[o], acc[m][o], 0, 0, 0);
        }
        __syncthreads();
    }
#pragma unroll
    for (int m = 0; m < 4; ++m) {
        int R0 = tM * 128 + wM * 64 + m * 16 + (lane >> 4) * 4;
#pragma unroll
        for (int o = 0; o < 4; ++o) {
            int Cc = tO * 128 + wO * 64 + o * 16 + (lane & 15);
            float cv = cvec[Cc];
#pragma unroll
            for (int r = 0; r < 4; ++r)
                C[(size_t)(R0 + r) * O + Cc] = acc[m][o][r] + cv;
        }
    }
}

// ---------------- set2set pieces ----------------
__global__ void k_wcat(const float* __restrict__ Wi, const float* __restrict__ Wh,
                       const float* __restrict__ bi, const float* __restrict__ bh,
                       u16* __restrict__ Wcat, float* __restrict__ bcat) {
    int o = blockIdx.x;
    int t = threadIdx.x;
    for (int c = t; c < 512; c += 256) Wcat[(size_t)o * 768 + c] = f2h(Wi[(size_t)o * 512 + c]);
    if (t < 256) Wcat[(size_t)o * 768 + 512 + t] = f2h(Wh[(size_t)o * 256 + t]);
    if (t == 0) bcat[o] = bi[o] + bh[o];
}

__global__ void k_lstm(const float* __restrict__ gates, float* __restrict__ cs,
                       float* __restrict__ hsb, u16* __restrict__ qsh, int G) {
    int idx = blockIdx.x * 256 + threadIdx.x;
    if (idx >= G * 256) return;
    int g = idx >> 8, d = idx & 255;
    const float* gt = &gates[(size_t)g * 1024];
    float gi = gt[d], gf = gt[256 + d], gg = gt[512 + d], go = gt[768 + d];
    float c = sigf(gf) * cs[idx] + sigf(gi) * tanhf(gg);
    float hh = sigf(go) * tanhf(c);
    cs[idx] = c;
    hsb[idx] = hh;
    u16 hb = f2h(hh);
    qsh[(size_t)g * 768 + d] = hb;
    qsh[(size_t)g * 768 + 512 + d] = hb;
}

// ---------------- attention: one wave per graph, no LDS, no syncthreads ----------------
__global__ __launch_bounds__(256) void k_attn2(const u16* __restrict__ h3,
                                               const float* __restrict__ hs,
                                               const int* __restrict__ gstart,
                                               u16* __restrict__ qsh, int G) {
    int wid = threadIdx.x >> 6, lane = threadIdx.x & 63;
    int g = blockIdx.x * 4 + wid;
    if (g >= G) return;
    int start = gstart[g], end = gstart[g + 1];

    f32x4 q = *(const f32x4*)&hs[(size_t)g * 256 + lane * 4];
    float m = -INFINITY, z = 0.f;
    float r0a = 0.f, r1a = 0.f, r2a = 0.f, r3a = 0.f;

    for (int c0 = start; c0 < end; c0 += 256) {
        int cn = min(256, end - c0);
        float e0 = 0.f, e1 = 0.f, e2 = 0.f, e3 = 0.f;
        float mc = m;

        auto pass1 = [&](int rr, float& ev) {
            int b = c0 + rr * 64;
            int nr = min(64, end - b);
            for (int ii = 0; ii < nr; ++ii) {
                u16x4 hv = *(const u16x4*)&h3[(size_t)(b + ii) * 256 + lane * 4];
                float e = h2f(hv[0]) * q[0] + h2f(hv[1]) * q[1] + h2f(hv[2]) * q[2] + h2f(hv[3]) * q[3];
                e += __shfl_xor(e, 32, 64);
                e += __shfl_xor(e, 16, 64);
                e += __shfl_xor(e, 8, 64);
                e += __shfl_xor(e, 4, 64);
                e += __shfl_xor(e, 2, 64);
                e += __shfl_xor(e, 1, 64);
                if (lane == ii) ev = e;
                mc = fmaxf(mc, e);
            }
        };
        pass1(0, e0);
        pass1(1, e1);
        pass1(2, e2);
        pass1(3, e3);

        float rf = (m == -INFINITY) ? 0.f : expf(m - mc);
        float zc = 0.f;
        e0 = (lane < cn) ? expf(e0 - mc) : 0.f;
        zc += e0;
        e1 = (64 + lane < cn) ? expf(e1 - mc) : 0.f;
        zc += e1;
        e2 = (128 + lane < cn) ? expf(e2 - mc) : 0.f;
        zc += e2;
        e3 = (192 + lane < cn) ? expf(e3 - mc) : 0.f;
        zc += e3;
        zc += __shfl_xor(zc, 32, 64);
        zc += __shfl_xor(zc, 16, 64);
        zc += __shfl_xor(zc, 8, 64);
        zc += __shfl_xor(zc, 4, 64);
        zc += __shfl_xor(zc, 2, 64);
        zc += __shfl_xor(zc, 1, 64);
        z = z * rf + zc;
        r0a *= rf; r1a *= rf; r2a *= rf; r3a *= rf;

        auto pass2 = [&](int rr, float ev) {
            int b = c0 + rr * 64;
            int nr = min(64, end - b);
            for (int ii = 0; ii < nr; ++ii) {
                float w = __shfl(ev, ii, 64);
                u16x4 hv = *(const u16x4*)&h3[(size_t)(b + ii) * 256 + lane * 4];
                r0a += w * h2f(hv[0]);
                r1a += w * h2f(hv[1]);
                r2a += w * h2f(hv[2]);
                r3a += w * h2f(hv[3]);
            }
        };
        pass2(0, e0);
        pass2(1, e1);
        pass2(2, e2);
        pass2(3, e3);
        m = mc;
    }
    float inv = (end > start) ? 1.f / fmaxf(z, 1e-30f) : 0.f;
    u16x4 o;
    o[0] = f2h(r0a * inv);
    o[1] = f2h(r1a * inv);
    o[2] = f2h(r2a * inv);
    o[3] = f2h(r3a * inv);
    *(u16x4*)&qsh[(size_t)g * 768 + 256 + lane * 4] = o;
}

// lin1/lin2 compose
__global__ void k_wfold(const float* __restrict__ l1W, const float* __restrict__ l1b,
                        const float* __restrict__ l2W, const float* __restrict__ l2b,
                        float* __restrict__ weff) {
    int c = blockIdx.x * 256 + threadIdx.x;
    if (c < 512) {
        float s = 0.f;
        for (int t = 0; t < 128; ++t) s += l2W[t] * l1W[(size_t)t * 512 + c];
        weff[c] = s;
    }
    if (c == 0) {
        float b = l2b[0];
        for (int t = 0; t < 128; ++t) b += l2W[t] * l1b[t];
        weff[512] = b;
    }
}

__global__ __launch_bounds__(256) void k_final2(const u16* __restrict__ qsh,
                                                const float* __restrict__ weff,
                                                float* __restrict__ out, int G) {
    __shared__ float wsm[513];
    int tid = threadIdx.x;
    for (int j = tid; j < 513; j += 256) wsm[j] = weff[j];
    __syncthreads();
    int g = blockIdx.x * 4 + (tid >> 6);
    int lane = tid & 63;
    if (g >= G) return;
    const u16* qp = &qsh[(size_t)g * 768];
    float s = 0.f;
#pragma unroll
    for (int j = 0; j < 8; ++j) s += h2f(qp[lane * 8 + j]) * wsm[lane * 8 + j];
    for (int off = 32; off; off >>= 1) s += __shfl_xor(s, off, 64);
    if (lane == 0) out[g] = sigf(s + wsm[512]);
}

// ---------------- host ----------------
extern "C" void kernel_launch(void* const* d_in, const int* in_sizes, int n_in,
                              void* d_out, int out_size, void* d_ws, size_t ws_size,
                              hipStream_t stream) {
    const int* x = (const int*)d_in[0];
    const int* ei = (const int*)d_in[1];
    const int* batch = (const int*)d_in[2];
    const float* atom_emb = (const float*)d_in[4];
    const float* W1 = (const float*)d_in[5];
    const float* b1 = (const float*)d_in[6];
    const float* W2 = (const float*)d_in[7];
    const float* b2 = (const float*)d_in[8];
    const float* W3 = (const float*)d_in[9];
    const float* b3 = (const float*)d_in[10];
    const float* gamma = (const float*)d_in[11];
    const float* beta = (const float*)d_in[12];
    const float* Wi = (const float*)d_in[13];
    const float* Wh = (const float*)d_in[14];
    const float* bi = (const float*)d_in[15];
    const float* bh = (const float*)d_in[16];
    const float* l1W = (const float*)d_in[17];
    const float* l1b = (const float*)d_in[18];
    const float* l2W = (const float*)d_in[19];
    const float* l2b = (const float*)d_in[20];

    const int N = in_sizes[0] / 9;
    const int E = in_sizes[1] / 2;
    const int G = out_size;
    const int* srcp = ei;
    const int* tgtp = ei + E;

    char* ws = (char*)d_ws;
    size_t off = 0;
    auto alloc = [&](size_t bytes) -> void* {
        void* p = ws + off;
        off += (bytes + 255) & ~(size_t)255;
        return p;
    };
    u16* X = (u16*)alloc((size_t)N * 256 * 2);  // 128 MiB
    int* rp = (int*)alloc((size_t)N * 4);
    int* esrc = (int*)alloc((size_t)E * 4);
    float* enorm = (float*)alloc((size_t)E * 4);
    float* dinv = (float*)alloc((size_t)N * 4);
    int* gstart = (int*)alloc((size_t)(G + 1) * 4);
    float* stats = (float*)alloc(512 * 4);
    float* stbuf = (float*)alloc(512 * 4);
    float* cvec = (float*)alloc(256 * 4);
    u16* Wp = (u16*)alloc(256 * 256 * 2);
    int* bsum = (int*)alloc(1024 * 4);
    float* weff = (float*)alloc(513 * 4);
    size_t offR = off;

    size_t o2 = offR;
    auto alloc2 = [&](size_t bytes) -> void* {
        void* p = ws + o2;
        o2 += (bytes + 255) & ~(size_t)255;
        return p;
    };
    u16* Wcat = (u16*)alloc2((size_t)1024 * 768 * 2);
    float* bcat = (float*)alloc2(1024 * 4);
    u16* qsh = (u16*)alloc2((size_t)G * 768 * 2);
    float* gates = (float*)alloc2((size_t)G * 1024 * 4);
    float* hsb = (float*)alloc2((size_t)G * 256 * 4);
    float* csb = (float*)alloc2((size_t)G * 256 * 4);
    size_t s2sR = o2 - offR;

    size_t bufBytes = ((size_t)N * 256 * 2 + 255) & ~(size_t)255;
    size_t qBytes = ((size_t)N * 64 * 2 + 255) & ~(size_t)255;
    size_t needDB = offR + (bufBytes > s2sR ? bufBytes : s2sR);
    size_t needQ = offR + (qBytes > s2sR ? qBytes : s2sR);
    bool useDB = ws_size >= needDB;
    if (!useDB && ws_size < needQ) {
        k_diagf<<<(G + 255) / 256, 256, 0, stream>>>((float*)d_out, G, 12345.0f);
        return;
    }
    u16* Y = (u16*)(ws + offR);

    // embed + segment starts + CSR
    k_embed<<<N, 256, 0, stream>>>(x, atom_emb, X, N);
    k_gstart<<<(N + 255) / 256, 256, 0, stream>>>(batch, gstart, N, G);
    k_zero_int<<<(N + 255) / 256, 256, 0, stream>>>(rp, N);
    k_count<<<(E + 255) / 256, 256, 0, stream>>>(tgtp, rp, E);
    k_dinv<<<(N + 255) / 256, 256, 0, stream>>>(rp, dinv, N);
    int nb1 = (N + 1023) / 1024;
    k_scan1<<<nb1, 256, 0, stream>>>(rp, bsum, N);
    k_scan2<<<1, 256, 0, stream>>>(bsum, nb1);
    k_scan3<<<(N + 255) / 256, 256, 0, stream>>>(rp, bsum, N);
    k_fill<<<(E + 255) / 256, 256, 0, stream>>>(srcp, tgtp, rp, dinv, esrc, enorm, E);

    int gipb = N / 64;
    int ccb = (N * 16 + 255) / 256;

    for (int conv = 0; conv < 3; ++conv) {
        const float* Wsrc = conv == 0 ? W1 : (conv == 1 ? W2 : W3);
        const float* bsrc = conv == 0 ? b1 : (conv == 1 ? b2 : b3);
        bool rs = conv < 2;
        if (conv == 0)
            k_cvtW<<<256, 256, 0, stream>>>(Wsrc, Wp, 65536);
        else
            k_fold<<<256, 256, 0, stream>>>(Wsrc, stbuf, Wp, cvec);
        if (rs) k_zero_f32<<<2, 256, 0, stream>>>(stats, 512);
        if (useDB) {
            k_gemm<<<gipb, 256, 0, stream>>>(X, Wp, conv ? cvec : nullptr, Y, N);
            if (rs)
                k_agg<true><<<1024, 256, 0, stream>>>(Y, rp, esrc, enorm, dinv, bsrc, X, stats, N);
            else
                k_agg<false><<<1024, 256, 0, stream>>>(Y, rp, esrc, enorm, dinv, bsrc, X, nullptr, N);
        } else {
            k_gemm<<<gipb, 256, 0, stream>>>(X, Wp, conv ? cvec : nullptr, X, N);
            for (int q = 0; q < 4; ++q) {
                k_copycol<<<ccb, 256, 0, stream>>>(X, Y, q, N);
                if (rs)
                    k_aggq<true><<<1024, 256, 0, stream>>>(Y, rp, esrc, enorm, dinv, bsrc, X, stats, q, N);
                else
                    k_aggq<false><<<1024, 256, 0, stream>>>(Y, rp, esrc, enorm, dinv, bsrc, X, nullptr, q, N);
            }
        }
        if (rs) k_bnparam<<<1, 256, 0, stream>>>(stats, gamma, beta, stbuf, N);
    }
    // h3 now in X

    // set2set
    k_wcat<<<1024, 256, 0, stream>>>(Wi, Wh, bi, bh, Wcat, bcat);
    k_zero_u16<<<(G * 768 + 255) / 256, 256, 0, stream>>>(qsh, G * 768);
    k_zero_f32<<<(G * 256 + 255) / 256, 256, 0, stream>>>(csb, G * 256);
    dim3 ggates(G / 128, 8);
    for (int s = 0; s < 4; ++s) {
        k_gemmf<<<ggates, 256, 0, stream>>>(qsh, Wcat, bcat, gates, G, 768, 1024);
        k_lstm<<<(G * 256 + 255) / 256, 256, 0, stream>>>(gates, csb, hsb, qsh, G);
        k_attn2<<<(G + 3) / 4, 256, 0, stream>>>(X, hsb, gstart, qsh, G);
    }
    k_wfold<<<2, 256, 0, stream>>>(l1W, l1b, l2W, l2b, weff);
    k_final2<<<(G + 3) / 4, 256, 0, stream>>>(qsh, weff, (float*)d_out, G);
}

// Round 9
// 2275.762 us; speedup vs baseline: 1.3622x; 1.0957x over previous
//
#include <hip/hip_runtime.h>
#include <hip/hip_bf16.h>
#include <math.h>

using u16 = unsigned short;
typedef __attribute__((ext_vector_type(8))) short short8;
typedef __attribute__((ext_vector_type(8))) _Float16 half8;
typedef __attribute__((ext_vector_type(4))) float f32x4;
typedef __attribute__((ext_vector_type(4))) u16 u16x4;

__device__ __constant__ int c_OFF[9] = {0, 119, 123, 135, 147, 157, 163, 169, 171};

__device__ __forceinline__ float h2f(u16 u) {
    _Float16 h;
    __builtin_memcpy(&h, &u, 2);
    return (float)h;
}
__device__ __forceinline__ u16 f2h(float f) {
    _Float16 h = (_Float16)f;
    u16 u;
    __builtin_memcpy(&u, &h, 2);
    return u;
}
__device__ __forceinline__ float sigf(float x) { return 1.f / (1.f + expf(-x)); }

// ---------------- diagnostics ----------------
__global__ void k_diagf(float* out, int G, float val) {
    int i = blockIdx.x * 256 + threadIdx.x;
    if (i < G) out[i] = val;
}

// ---------------- zero helpers ----------------
__global__ void k_zero_f32(float* p, int n) {
    int i = blockIdx.x * 256 + threadIdx.x;
    if (i < n) p[i] = 0.f;
}
__global__ void k_zero_u16(u16* p, int n) {
    int i = blockIdx.x * 256 + threadIdx.x;
    if (i < n) p[i] = 0;
}
__global__ void k_zero_int(int* p, int n) {
    int i = blockIdx.x * 256 + threadIdx.x;
    if (i < n) p[i] = 0;
}

// ---------------- fp32 -> fp16 convert ----------------
__global__ void k_cvtW(const float* __restrict__ src, u16* __restrict__ dst, int n) {
    int i = blockIdx.x * 256 + threadIdx.x;
    if (i < n) dst[i] = f2h(src[i]);
}

// ---------------- atom encoder: 8 nodes/block, 8 cols/thread, vectorized ----------------
__global__ __launch_bounds__(256) void k_embed(const int* __restrict__ x,
                                               const float* __restrict__ emb,
                                               u16* __restrict__ out, int N) {
    __shared__ int rows[72];
    int nb = blockIdx.x * 8;
    int tid = threadIdx.x;
    if (tid < 72) rows[tid] = x[(size_t)nb * 9 + tid] + c_OFF[tid % 9];
    __syncthreads();
    int ln = tid >> 5;
    int c8 = (tid & 31) * 8;
    float s0 = 0.f, s1 = 0.f, s2 = 0.f, s3 = 0.f, s4 = 0.f, s5 = 0.f, s6 = 0.f, s7 = 0.f;
#pragma unroll
    for (int c = 0; c < 9; ++c) {
        int r = rows[ln * 9 + c];
        f32x4 a = *(const f32x4*)&emb[r * 256 + c8];
        f32x4 b = *(const f32x4*)&emb[r * 256 + c8 + 4];
        s0 += a[0]; s1 += a[1]; s2 += a[2]; s3 += a[3];
        s4 += b[0]; s5 += b[1]; s6 += b[2]; s7 += b[3];
    }
    short8 o;
    o[0] = (short)f2h(s0); o[1] = (short)f2h(s1); o[2] = (short)f2h(s2); o[3] = (short)f2h(s3);
    o[4] = (short)f2h(s4); o[5] = (short)f2h(s5); o[6] = (short)f2h(s6); o[7] = (short)f2h(s7);
    *(short8*)&out[(size_t)(nb + ln) * 256 + c8] = o;
}

// ---------------- graph segment starts from sorted batch ----------------
__global__ void k_gstart(const int* __restrict__ batch, int* __restrict__ gstart, int N, int G) {
    int i = blockIdx.x * 256 + threadIdx.x;
    if (i >= N) return;
    int b = batch[i];
    if (i == 0) {
        for (int g = 0; g <= b; ++g) gstart[g] = 0;
    } else {
        int p = batch[i - 1];
        for (int g = p + 1; g <= b; ++g) gstart[g] = i;
    }
    if (i == N - 1) {
        for (int g = b + 1; g <= G; ++g) gstart[g] = N;
    }
}

// ---------------- CSR build (in-place in rp) ----------------
__global__ void k_count(const int* __restrict__ tgt, int* rp, int E) {
    int e = blockIdx.x * 256 + threadIdx.x;
    if (e < E) atomicAdd(&rp[tgt[e]], 1);
}

__global__ void k_dinv(const int* __restrict__ cnt, float* __restrict__ dinv, int N) {
    int i = blockIdx.x * 256 + threadIdx.x;
    if (i < N) dinv[i] = rsqrtf((float)cnt[i] + 1.f);
}

__global__ void k_scan1(int* __restrict__ rp, int* __restrict__ bsum, int N) {
    int t = threadIdx.x;
    int base = blockIdx.x * 1024 + t * 4;
    int v0 = 0, v1 = 0, v2 = 0, v3 = 0;
    if (base + 3 < N) {
        v0 = rp[base]; v1 = rp[base + 1]; v2 = rp[base + 2]; v3 = rp[base + 3];
    } else {
        if (base < N) v0 = rp[base];
        if (base + 1 < N) v1 = rp[base + 1];
        if (base + 2 < N) v2 = rp[base + 2];
    }
    int s = v0 + v1 + v2 + v3;
    int lane = t & 63, w = t >> 6;
    int x = s;
    for (int o = 1; o < 64; o <<= 1) {
        int y = __shfl_up(x, o, 64);
        if (lane >= o) x += y;
    }
    __shared__ int wsum[4];
    if (lane == 63) wsum[w] = x;
    __syncthreads();
    int woff = 0;
    for (int i = 0; i < w; ++i) woff += wsum[i];
    int excl = woff + x - s;
    if (base < N) rp[base] = excl;
    if (base + 1 < N) rp[base + 1] = excl + v0;
    if (base + 2 < N) rp[base + 2] = excl + v0 + v1;
    if (base + 3 < N) rp[base + 3] = excl + v0 + v1 + v2;
    if (t == 255) bsum[blockIdx.x] = wsum[0] + wsum[1] + wsum[2] + wsum[3];
}

__global__ void k_scan2(int* bsum, int nb) {
    int t = threadIdx.x;
    int s = (t < nb) ? bsum[t] : 0;
    int lane = t & 63, w = t >> 6;
    int x = s;
    for (int o = 1; o < 64; o <<= 1) {
        int y = __shfl_up(x, o, 64);
        if (lane >= o) x += y;
    }
    __shared__ int wsum[4];
    if (lane == 63) wsum[w] = x;
    __syncthreads();
    int woff = 0;
    for (int i = 0; i < w; ++i) woff += wsum[i];
    if (t < nb) bsum[t] = woff + x - s;
}

__global__ void k_scan3(int* __restrict__ rp, const int* __restrict__ bsum, int N) {
    int i = blockIdx.x * 256 + threadIdx.x;
    if (i < N) rp[i] += bsum[i >> 10];
}

// fill with per-edge norm; afterwards rp[n] = end(n), start(n) = rp[n-1]
__global__ void k_fill(const int* __restrict__ src, const int* __restrict__ tgt,
                       int* __restrict__ rp, const float* __restrict__ dinv,
                       int* __restrict__ esrc, float* __restrict__ enorm, int E) {
    int e = blockIdx.x * 256 + threadIdx.x;
    if (e < E) {
        int t = tgt[e];
        int s = src[e];
        int p = atomicAdd(&rp[t], 1);
        esrc[p] = s;
        enorm[p] = dinv[s] * dinv[t];
    }
}

// ---------------- GEMM: OUT[64 rows] <- Xin[64 rows] @ Wp^T (+cvec); OUT may equal Xin ----------------
__global__ __launch_bounds__(256, 3) void k_gemm(const u16* __restrict__ Xin,
                                                 const u16* __restrict__ W,
                                                 const float* __restrict__ cvec,
                                                 u16* __restrict__ out, int N) {
    __shared__ u16 As[64][260];
    __shared__ u16 Ws[256][36];
    int r0 = blockIdx.x * 64;
    int tid = threadIdx.x, lane = tid & 63, w = tid >> 6;
#pragma unroll
    for (int i = 0; i < 8; ++i) {
        int chunk = i * 256 + tid;
        int r = chunk >> 5, c8 = chunk & 31;
        *(short8*)&As[r][c8 * 8] = *(const short8*)&Xin[(size_t)(r0 + r) * 256 + c8 * 8];
    }
    f32x4 acc[16];
#pragma unroll
    for (int o = 0; o < 16; ++o) acc[o] = f32x4{0.f, 0.f, 0.f, 0.f};
    for (int k0 = 0; k0 < 256; k0 += 32) {
        __syncthreads();
#pragma unroll
        for (int i = 0; i < 4; ++i) {
            int chunk = i * 256 + tid;
            int r = chunk >> 2, c8 = chunk & 3;
            *(short8*)&Ws[r][c8 * 8] = *(const short8*)&W[(size_t)r * 256 + k0 + c8 * 8];
        }
        __syncthreads();
        half8 af = *(const half8*)&As[w * 16 + (lane & 15)][k0 + (lane >> 4) * 8];
#pragma unroll
        for (int o = 0; o < 16; ++o) {
            half8 wf = *(const half8*)&Ws[o * 16 + (lane & 15)][(lane >> 4) * 8];
            acc[o] = __builtin_amdgcn_mfma_f32_16x16x32_f16(af, wf, acc[o], 0, 0, 0);
        }
    }
    __syncthreads();
#pragma unroll
    for (int o = 0; o < 16; ++o) {
        int col = o * 16 + (lane & 15);
        float cv = cvec ? cvec[col] : 0.f;
#pragma unroll
        for (int r = 0; r < 4; ++r) {
            int row = w * 16 + (lane >> 4) * 4 + r;
            As[row][col] = f2h(acc[o][r] + cv);
        }
    }
    __syncthreads();
#pragma unroll
    for (int i = 0; i < 8; ++i) {
        int chunk = i * 256 + tid;
        int r = chunk >> 5, c8 = chunk & 31;
        *(short8*)&out[(size_t)(r0 + r) * 256 + c8 * 8] = *(const short8*)&As[r][c8 * 8];
    }
}

// ---------------- full-width aggregation (DB path) ----------------
template <bool RS>
__global__ __launch_bounds__(256) void k_agg(const u16* __restrict__ hw,
                                             const int* __restrict__ rp,
                                             const int* __restrict__ esrc,
                                             const float* __restrict__ enorm,
                                             const float* __restrict__ dinv,
                                             const float* __restrict__ bias,
                                             u16* __restrict__ X,
                                             float* __restrict__ stats, int N) {
    int lane = threadIdx.x & 63;
    int gw = blockIdx.x * 4 + (threadIdx.x >> 6);
    int nw = gridDim.x * 4;
    float bv[4];
#pragma unroll
    for (int j = 0; j < 4; ++j) bv[j] = bias[lane * 4 + j];
    float ss[4] = {0, 0, 0, 0}, qq[4] = {0, 0, 0, 0};
    for (int n = gw; n < N; n += nw) {
        int end = rp[n];
        int start = n ? rp[n - 1] : 0;
        float dn = dinv[n];
        u16x4 hv = *(const u16x4*)&hw[(size_t)n * 256 + lane * 4];
        float a[4];
#pragma unroll
        for (int j = 0; j < 4; ++j) a[j] = h2f(hv[j]) * dn * dn + bv[j];
        for (int j = start; j < end; ++j) {
            int s = esrc[j];
            float nr = enorm[j];
            u16x4 v = *(const u16x4*)&hw[(size_t)s * 256 + lane * 4];
#pragma unroll
            for (int jj = 0; jj < 4; ++jj) a[jj] += h2f(v[jj]) * nr;
        }
        u16x4 o;
#pragma unroll
        for (int j = 0; j < 4; ++j) {
            if (RS) {
                a[j] = fmaxf(a[j], 0.f);
                ss[j] += a[j];
                qq[j] += a[j] * a[j];
            }
            o[j] = f2h(a[j]);
        }
        *(u16x4*)&X[(size_t)n * 256 + lane * 4] = o;
    }
    if (RS) {
        __shared__ float sh[512];
        int t = threadIdx.x;
        sh[t] = 0.f;
        sh[t + 256] = 0.f;
        __syncthreads();
#pragma unroll
        for (int j = 0; j < 4; ++j) {
            atomicAdd(&sh[lane * 4 + j], ss[j]);
            atomicAdd(&sh[256 + lane * 4 + j], qq[j]);
        }
        __syncthreads();
        atomicAdd(&stats[t], sh[t]);
        atomicAdd(&stats[t + 256], sh[t + 256]);
    }
}

// ---------------- Q-path: snapshot + quarter aggregation (fallback) ----------------
__global__ void k_copycol(const u16* __restrict__ X, u16* __restrict__ Q, int q, int N) {
    int i = blockIdx.x * 256 + threadIdx.x;
    if (i >= N * 16) return;
    int n = i >> 4, c4 = (i & 15) * 4;
    *(u16x4*)&Q[(size_t)n * 64 + c4] = *(const u16x4*)&X[(size_t)n * 256 + q * 64 + c4];
}

template <bool RS>
__global__ __launch_bounds__(256) void k_aggq(const u16* __restrict__ Q,
                                              const int* __restrict__ rp,
                                              const int* __restrict__ esrc,
                                              const float* __restrict__ enorm,
                                              const float* __restrict__ dinv,
                                              const float* __restrict__ bias,
                                              u16* __restrict__ X,
                                              float* __restrict__ stats, int q, int N) {
    int lane = threadIdx.x & 63;
    int gw = blockIdx.x * 4 + (threadIdx.x >> 6);
    int nw = gridDim.x * 4;
    int col = q * 64 + lane;
    float bv = bias[col];
    float ss = 0.f, qq = 0.f;
    for (int n = gw; n < N; n += nw) {
        int end = rp[n];
        int start = n ? rp[n - 1] : 0;
        float dn = dinv[n];
        float a = h2f(Q[(size_t)n * 64 + lane]) * dn * dn + bv;
        for (int j = start; j < end; ++j) {
            int s = esrc[j];
            a += h2f(Q[(size_t)s * 64 + lane]) * enorm[j];
        }
        if (RS) {
            a = fmaxf(a, 0.f);
            ss += a;
            qq += a * a;
        }
        X[(size_t)n * 256 + col] = f2h(a);
    }
    if (RS) {
        __shared__ float sh[128];
        int t = threadIdx.x;
        if (t < 128) sh[t] = 0.f;
        __syncthreads();
        atomicAdd(&sh[lane], ss);
        atomicAdd(&sh[64 + lane], qq);
        __syncthreads();
        if (t < 64) {
            atomicAdd(&stats[col], sh[lane]);
            atomicAdd(&stats[256 + col], sh[64 + lane]);
        }
    }
}

__global__ void k_bnparam(const float* __restrict__ stats, const float* __restrict__ gamma,
                          const float* __restrict__ beta, float* __restrict__ st, int N) {
    int d = threadIdx.x;
    float inv = 1.f / (float)N;
    float mu = stats[d] * inv;
    float var = fmaxf(stats[256 + d] * inv - mu * mu, 0.f);
    float sc = gamma[d] * rsqrtf(var + 1e-5f);
    st[d] = sc;
    st[256 + d] = beta[d] - mu * sc;
}

__global__ void k_fold(const float* __restrict__ W, const float* __restrict__ st,
                       u16* __restrict__ Wp, float* __restrict__ cvec) {
    __shared__ float red[256];
    int o = blockIdx.x, k = threadIdx.x;
    float w = W[o * 256 + k];
    Wp[o * 256 + k] = f2h(w * st[k]);
    red[k] = w * st[256 + k];
    __syncthreads();
    for (int s = 128; s > 0; s >>= 1) {
        if (k < s) red[k] += red[k + s];
        __syncthreads();
    }
    if (k == 0) cvec[o] = red[0];
}

// ---------------- set2set GEMM: C[M,O](f32) = A[M,K](fp16) @ W[O,K](fp16)^T + cvec ----------------
__global__ __launch_bounds__(256, 2) void k_gemmf(const u16* __restrict__ A,
                                                  const u16* __restrict__ W,
                                                  const float* __restrict__ cvec,
                                                  float* __restrict__ C, int M, int K, int O) {
    const int PAD = 8;
    __shared__ u16 As[128][64 + PAD];
    __shared__ u16 Ws[128][64 + PAD];
    int tM = blockIdx.x, tO = blockIdx.y;
    int tid = threadIdx.x;
    int lane = tid & 63, wid = tid >> 6;
    int wM = wid & 1, wO = wid >> 1;
    f32x4 acc[4][4] = {};
    size_t rowA0 = (size_t)tM * 128, rowW0 = (size_t)tO * 128;
    for (int k0 = 0; k0 < K; k0 += 64) {
#pragma unroll
        for (int i = 0; i < 4; ++i) {
            int chunk = tid + i * 256;
            int r = chunk >> 3, c16 = chunk & 7;
            *(short8*)&As[r][c16 * 8] = *(const short8*)&A[(rowA0 + r) * K + k0 + c16 * 8];
            *(short8*)&Ws[r][c16 * 8] = *(const short8*)&W[(rowW0 + r) * K + k0 + c16 * 8];
        }
        __syncthreads();
#pragma unroll
        for (int ks = 0; ks < 2; ++ks) {
            half8 af[4], wf[4];
#pragma unroll
            for (int m = 0; m < 4; ++m)
                af[m] = *(const half8*)&As[wM * 64 + m * 16 + (lane & 15)][ks * 32 + (lane >> 4) * 8];
#pragma unroll
            for (int o = 0; o < 4; ++o)
                wf[o] = *(const half8*)&Ws[wO * 64 + o * 16 + (lane & 15)][ks * 32 + (lane >> 4) * 8];
#pragma unroll
            for (int m = 0; m < 4; ++m)
#pragma unroll
                for (int o = 0; o < 4; ++o)
                    acc[m][o] = __builtin_amdgcn_mfma_f32_16x16x32_f16(af[m], wf[o], acc[m][o], 0, 0, 0);
        }
        __syncthreads();
    }
#pragma unroll
    for (int m = 0; m < 4; ++m) {
        int R0 = tM * 128 + wM * 64 + m * 16 + (lane >> 4) * 4;
#pragma unroll
        for (int o = 0; o < 4; ++o) {
            int Cc = tO * 128 + wO * 64 + o * 16 + (lane & 15);
            float cv = cvec[Cc];
#pragma unroll
            for (int r = 0; r < 4; ++r)
                C[(size_t)(R0 + r) * O + Cc] = acc[m][o][r] + cv;
        }
    }
}

// ---------------- set2set pieces ----------------
__global__ void k_wcat(const float* __restrict__ Wi, const float* __restrict__ Wh,
                       const float* __restrict__ bi, const float* __restrict__ bh,
                       u16* __restrict__ Wcat, float* __restrict__ bcat) {
    int o = blockIdx.x;
    int t = threadIdx.x;
    for (int c = t; c < 512; c += 256) Wcat[(size_t)o * 768 + c] = f2h(Wi[(size_t)o * 512 + c]);
    if (t < 256) Wcat[(size_t)o * 768 + 512 + t] = f2h(Wh[(size_t)o * 256 + t]);
    if (t == 0) bcat[o] = bi[o] + bh[o];
}

__global__ void k_lstm(const float* __restrict__ gates, float* __restrict__ cs,
                       float* __restrict__ hsb, u16* __restrict__ qsh, int G) {
    int idx = blockIdx.x * 256 + threadIdx.x;
    if (idx >= G * 256) return;
    int g = idx >> 8, d = idx & 255;
    const float* gt = &gates[(size_t)g * 1024];
    float gi = gt[d], gf = gt[256 + d], gg = gt[512 + d], go = gt[768 + d];
    float c = sigf(gf) * cs[idx] + sigf(gi) * tanhf(gg);
    float hh = sigf(go) * tanhf(c);
    cs[idx] = c;
    hsb[idx] = hh;
    u16 hb = f2h(hh);
    qsh[(size_t)g * 768 + d] = hb;
    qsh[(size_t)g * 768 + 512 + d] = hb;
}

// ---------------- attention: one wave per graph, no LDS, no syncthreads ----------------
__global__ __launch_bounds__(256) void k_attn2(const u16* __restrict__ h3,
                                               const float* __restrict__ hs,
                                               const int* __restrict__ gstart,
                                               u16* __restrict__ qsh, int G) {
    int wid = threadIdx.x >> 6, lane = threadIdx.x & 63;
    int g = blockIdx.x * 4 + wid;
    if (g >= G) return;
    int start = gstart[g], end = gstart[g + 1];

    f32x4 q = *(const f32x4*)&hs[(size_t)g * 256 + lane * 4];
    float m = -INFINITY, z = 0.f;
    float r0a = 0.f, r1a = 0.f, r2a = 0.f, r3a = 0.f;

    for (int c0 = start; c0 < end; c0 += 256) {
        int cn = min(256, end - c0);
        float e0 = 0.f, e1 = 0.f, e2 = 0.f, e3 = 0.f;
        float mc = m;

        auto pass1 = [&](int rr, float& ev) {
            int b = c0 + rr * 64;
            int nr = min(64, end - b);
            for (int ii = 0; ii < nr; ++ii) {
                u16x4 hv = *(const u16x4*)&h3[(size_t)(b + ii) * 256 + lane * 4];
                float e = h2f(hv[0]) * q[0] + h2f(hv[1]) * q[1] + h2f(hv[2]) * q[2] + h2f(hv[3]) * q[3];
                e += __shfl_xor(e, 32, 64);
                e += __shfl_xor(e, 16, 64);
                e += __shfl_xor(e, 8, 64);
                e += __shfl_xor(e, 4, 64);
                e += __shfl_xor(e, 2, 64);
                e += __shfl_xor(e, 1, 64);
                if (lane == ii) ev = e;
                mc = fmaxf(mc, e);
            }
        };
        pass1(0, e0);
        pass1(1, e1);
        pass1(2, e2);
        pass1(3, e3);

        float rf = (m == -INFINITY) ? 0.f : expf(m - mc);
        float zc = 0.f;
        e0 = (lane < cn) ? expf(e0 - mc) : 0.f;
        zc += e0;
        e1 = (64 + lane < cn) ? expf(e1 - mc) : 0.f;
        zc += e1;
        e2 = (128 + lane < cn) ? expf(e2 - mc) : 0.f;
        zc += e2;
        e3 = (192 + lane < cn) ? expf(e3 - mc) : 0.f;
        zc += e3;
        zc += __shfl_xor(zc, 32, 64);
        zc += __shfl_xor(zc, 16, 64);
        zc += __shfl_xor(zc, 8, 64);
        zc += __shfl_xor(zc, 4, 64);
        zc += __shfl_xor(zc, 2, 64);
        zc += __shfl_xor(zc, 1, 64);
        z = z * rf + zc;
        r0a *= rf; r1a *= rf; r2a *= rf; r3a *= rf;

        auto pass2 = [&](int rr, float ev) {
            int b = c0 + rr * 64;
            int nr = min(64, end - b);
            for (int ii = 0; ii < nr; ++ii) {
                float w = __shfl(ev, ii, 64);
                u16x4 hv = *(const u16x4*)&h3[(size_t)(b + ii) * 256 + lane * 4];
                r0a += w * h2f(hv[0]);
                r1a += w * h2f(hv[1]);
                r2a += w * h2f(hv[2]);
                r3a += w * h2f(hv[3]);
            }
        };
        pass2(0, e0);
        pass2(1, e1);
        pass2(2, e2);
        pass2(3, e3);
        m = mc;
    }
    float inv = (end > start) ? 1.f / fmaxf(z, 1e-30f) : 0.f;
    u16x4 o;
    o[0] = f2h(r0a * inv);
    o[1] = f2h(r1a * inv);
    o[2] = f2h(r2a * inv);
    o[3] = f2h(r3a * inv);
    *(u16x4*)&qsh[(size_t)g * 768 + 256 + lane * 4] = o;
}

// lin1/lin2 compose
__global__ void k_wfold(const float* __restrict__ l1W, const float* __restrict__ l1b,
                        const float* __restrict__ l2W, const float* __restrict__ l2b,
                        float* __restrict__ weff) {
    int c = blockIdx.x * 256 + threadIdx.x;
    if (c < 512) {
        float s = 0.f;
        for (int t = 0; t < 128; ++t) s += l2W[t] * l1W[(size_t)t * 512 + c];
        weff[c] = s;
    }
    if (c == 0) {
        float b = l2b[0];
        for (int t = 0; t < 128; ++t) b += l2W[t] * l1b[t];
        weff[512] = b;
    }
}

__global__ __launch_bounds__(256) void k_final2(const u16* __restrict__ qsh,
                                                const float* __restrict__ weff,
                                                float* __restrict__ out, int G) {
    __shared__ float wsm[513];
    int tid = threadIdx.x;
    for (int j = tid; j < 513; j += 256) wsm[j] = weff[j];
    __syncthreads();
    int g = blockIdx.x * 4 + (tid >> 6);
    int lane = tid & 63;
    if (g >= G) return;
    const u16* qp = &qsh[(size_t)g * 768];
    float s = 0.f;
#pragma unroll
    for (int j = 0; j < 8; ++j) s += h2f(qp[lane * 8 + j]) * wsm[lane * 8 + j];
    for (int off = 32; off; off >>= 1) s += __shfl_xor(s, off, 64);
    if (lane == 0) out[g] = sigf(s + wsm[512]);
}

// ---------------- host ----------------
extern "C" void kernel_launch(void* const* d_in, const int* in_sizes, int n_in,
                              void* d_out, int out_size, void* d_ws, size_t ws_size,
                              hipStream_t stream) {
    const int* x = (const int*)d_in[0];
    const int* ei = (const int*)d_in[1];
    const int* batch = (const int*)d_in[2];
    const float* atom_emb = (const float*)d_in[4];
    const float* W1 = (const float*)d_in[5];
    const float* b1 = (const float*)d_in[6];
    const float* W2 = (const float*)d_in[7];
    const float* b2 = (const float*)d_in[8];
    const float* W3 = (const float*)d_in[9];
    const float* b3 = (const float*)d_in[10];
    const float* gamma = (const float*)d_in[11];
    const float* beta = (const float*)d_in[12];
    const float* Wi = (const float*)d_in[13];
    const float* Wh = (const float*)d_in[14];
    const float* bi = (const float*)d_in[15];
    const float* bh = (const float*)d_in[16];
    const float* l1W = (const float*)d_in[17];
    const float* l1b = (const float*)d_in[18];
    const float* l2W = (const float*)d_in[19];
    const float* l2b = (const float*)d_in[20];

    const int N = in_sizes[0] / 9;
    const int E = in_sizes[1] / 2;
    const int G = out_size;
    const int* srcp = ei;
    const int* tgtp = ei + E;

    char* ws = (char*)d_ws;
    size_t off = 0;
    auto alloc = [&](size_t bytes) -> void* {
        void* p = ws + off;
        off += (bytes + 255) & ~(size_t)255;
        return p;
    };
    u16* X = (u16*)alloc((size_t)N * 256 * 2);  // 128 MiB
    int* rp = (int*)alloc((size_t)N * 4);
    int* esrc = (int*)alloc((size_t)E * 4);
    float* enorm = (float*)alloc((size_t)E * 4);
    float* dinv = (float*)alloc((size_t)N * 4);
    int* gstart = (int*)alloc((size_t)(G + 1) * 4);
    float* stats = (float*)alloc(512 * 4);
    float* stbuf = (float*)alloc(512 * 4);
    float* cvec = (float*)alloc(256 * 4);
    u16* Wp = (u16*)alloc(256 * 256 * 2);
    int* bsum = (int*)alloc(1024 * 4);
    float* weff = (float*)alloc(513 * 4);
    size_t offR = off;

    size_t o2 = offR;
    auto alloc2 = [&](size_t bytes) -> void* {
        void* p = ws + o2;
        o2 += (bytes + 255) & ~(size_t)255;
        return p;
    };
    u16* Wcat = (u16*)alloc2((size_t)1024 * 768 * 2);
    float* bcat = (float*)alloc2(1024 * 4);
    u16* qsh = (u16*)alloc2((size_t)G * 768 * 2);
    float* gates = (float*)alloc2((size_t)G * 1024 * 4);
    float* hsb = (float*)alloc2((size_t)G * 256 * 4);
    float* csb = (float*)alloc2((size_t)G * 256 * 4);
    size_t s2sR = o2 - offR;

    size_t bufBytes = ((size_t)N * 256 * 2 + 255) & ~(size_t)255;
    size_t qBytes = ((size_t)N * 64 * 2 + 255) & ~(size_t)255;
    size_t needDB = offR + (bufBytes > s2sR ? bufBytes : s2sR);
    size_t needQ = offR + (qBytes > s2sR ? qBytes : s2sR);
    bool useDB = ws_size >= needDB;
    if (!useDB && ws_size < needQ) {
        k_diagf<<<(G + 255) / 256, 256, 0, stream>>>((float*)d_out, G, 12345.0f);
        return;
    }
    u16* Y = (u16*)(ws + offR);

    // embed + segment starts + CSR
    k_embed<<<N / 8, 256, 0, stream>>>(x, atom_emb, X, N);
    k_gstart<<<(N + 255) / 256, 256, 0, stream>>>(batch, gstart, N, G);
    k_zero_int<<<(N + 255) / 256, 256, 0, stream>>>(rp, N);
    k_count<<<(E + 255) / 256, 256, 0, stream>>>(tgtp, rp, E);
    k_dinv<<<(N + 255) / 256, 256, 0, stream>>>(rp, dinv, N);
    int nb1 = (N + 1023) / 1024;
    k_scan1<<<nb1, 256, 0, stream>>>(rp, bsum, N);
    k_scan2<<<1, 256, 0, stream>>>(bsum, nb1);
    k_scan3<<<(N + 255) / 256, 256, 0, stream>>>(rp, bsum, N);
    k_fill<<<(E + 255) / 256, 256, 0, stream>>>(srcp, tgtp, rp, dinv, esrc, enorm, E);

    int gipb = N / 64;
    int ccb = (N * 16 + 255) / 256;
    const int AGGB = 4096;

    for (int conv = 0; conv < 3; ++conv) {
        const float* Wsrc = conv == 0 ? W1 : (conv == 1 ? W2 : W3);
        const float* bsrc = conv == 0 ? b1 : (conv == 1 ? b2 : b3);
        bool rs = conv < 2;
        if (conv == 0)
            k_cvtW<<<256, 256, 0, stream>>>(Wsrc, Wp, 65536);
        else
            k_fold<<<256, 256, 0, stream>>>(Wsrc, stbuf, Wp, cvec);
        if (rs) k_zero_f32<<<2, 256, 0, stream>>>(stats, 512);
        if (useDB) {
            k_gemm<<<gipb, 256, 0, stream>>>(X, Wp, conv ? cvec : nullptr, Y, N);
            if (rs)
                k_agg<true><<<AGGB, 256, 0, stream>>>(Y, rp, esrc, enorm, dinv, bsrc, X, stats, N);
            else
                k_agg<false><<<AGGB, 256, 0, stream>>>(Y, rp, esrc, enorm, dinv, bsrc, X, nullptr, N);
        } else {
            k_gemm<<<gipb, 256, 0, stream>>>(X, Wp, conv ? cvec : nullptr, X, N);
            for (int q = 0; q < 4; ++q) {
                k_copycol<<<ccb, 256, 0, stream>>>(X, Y, q, N);
                if (rs)
                    k_aggq<true><<<AGGB, 256, 0, stream>>>(Y, rp, esrc, enorm, dinv, bsrc, X, stats, q, N);
                else
                    k_aggq<false><<<AGGB, 256, 0, stream>>>(Y, rp, esrc, enorm, dinv, bsrc, X, nullptr, q, N);
            }
        }
        if (rs) k_bnparam<<<1, 256, 0, stream>>>(stats, gamma, beta, stbuf, N);
    }
    // h3 now in X

    // set2set
    k_wcat<<<1024, 256, 0, stream>>>(Wi, Wh, bi, bh, Wcat, bcat);
    k_zero_u16<<<(G * 768 + 255) / 256, 256, 0, stream>>>(qsh, G * 768);
    k_zero_f32<<<(G * 256 + 255) / 256, 256, 0, stream>>>(csb, G * 256);
    dim3 ggates(G / 128, 8);
    for (int s = 0; s < 4; ++s) {
        k_gemmf<<<ggates, 256, 0, stream>>>(qsh, Wcat, bcat, gates, G, 768, 1024);
        k_lstm<<<(G * 256 + 255) / 256, 256, 0, stream>>>(gates, csb, hsb, qsh, G);
        k_attn2<<<(G + 3) / 4, 256, 0, stream>>>(X, hsb, gstart, qsh, G);
    }
    k_wfold<<<2, 256, 0, stream>>>(l1W, l1b, l2W, l2b, weff);
    k_final2<<<(G + 3) / 4, 256, 0, stream>>>(qsh, weff, (float*)d_out, G);
}

// Round 10
// 1582.019 us; speedup vs baseline: 1.9596x; 1.4385x over previous
//
#include <hip/hip_runtime.h>
#include <hip/hip_bf16.h>
#include <math.h>

using u16 = unsigned short;
typedef __attribute__((ext_vector_type(8))) short short8;
typedef __attribute__((ext_vector_type(8))) _Float16 half8;
typedef __attribute__((ext_vector_type(4))) float f32x4;
typedef __attribute__((ext_vector_type(4))) u16 u16x4;

__device__ __constant__ int c_OFF[9] = {0, 119, 123, 135, 147, 157, 163, 169, 171};

__device__ __forceinline__ float h2f(u16 u) {
    _Float16 h;
    __builtin_memcpy(&h, &u, 2);
    return (float)h;
}
__device__ __forceinline__ u16 f2h(float f) {
    _Float16 h = (_Float16)f;
    u16 u;
    __builtin_memcpy(&u, &h, 2);
    return u;
}
__device__ __forceinline__ float sigf(float x) { return 1.f / (1.f + expf(-x)); }

// ---------------- diagnostics ----------------
__global__ void k_diagf(float* out, int G, float val) {
    int i = blockIdx.x * 256 + threadIdx.x;
    if (i < G) out[i] = val;
}

// ---------------- zero helpers ----------------
__global__ void k_zero_f32(float* p, int n) {
    int i = blockIdx.x * 256 + threadIdx.x;
    if (i < n) p[i] = 0.f;
}
__global__ void k_zero_u16(u16* p, int n) {
    int i = blockIdx.x * 256 + threadIdx.x;
    if (i < n) p[i] = 0;
}
__global__ void k_zero_int(int* p, int n) {
    int i = blockIdx.x * 256 + threadIdx.x;
    if (i < n) p[i] = 0;
}

// ---------------- fp32 -> fp16 convert ----------------
__global__ void k_cvtW(const float* __restrict__ src, u16* __restrict__ dst, int n) {
    int i = blockIdx.x * 256 + threadIdx.x;
    if (i < n) dst[i] = f2h(src[i]);
}

// ---------------- atom encoder: 8 nodes/block, 8 cols/thread, vectorized ----------------
__global__ __launch_bounds__(256) void k_embed(const int* __restrict__ x,
                                               const float* __restrict__ emb,
                                               u16* __restrict__ out, int N) {
    __shared__ int rows[72];
    int nb = blockIdx.x * 8;
    int tid = threadIdx.x;
    if (tid < 72) rows[tid] = x[(size_t)nb * 9 + tid] + c_OFF[tid % 9];
    __syncthreads();
    int ln = tid >> 5;
    int c8 = (tid & 31) * 8;
    float s0 = 0.f, s1 = 0.f, s2 = 0.f, s3 = 0.f, s4 = 0.f, s5 = 0.f, s6 = 0.f, s7 = 0.f;
#pragma unroll
    for (int c = 0; c < 9; ++c) {
        int r = rows[ln * 9 + c];
        f32x4 a = *(const f32x4*)&emb[r * 256 + c8];
        f32x4 b = *(const f32x4*)&emb[r * 256 + c8 + 4];
        s0 += a[0]; s1 += a[1]; s2 += a[2]; s3 += a[3];
        s4 += b[0]; s5 += b[1]; s6 += b[2]; s7 += b[3];
    }
    short8 o;
    o[0] = (short)f2h(s0); o[1] = (short)f2h(s1); o[2] = (short)f2h(s2); o[3] = (short)f2h(s3);
    o[4] = (short)f2h(s4); o[5] = (short)f2h(s5); o[6] = (short)f2h(s6); o[7] = (short)f2h(s7);
    *(short8*)&out[(size_t)(nb + ln) * 256 + c8] = o;
}

// ---------------- graph segment starts from sorted batch ----------------
__global__ void k_gstart(const int* __restrict__ batch, int* __restrict__ gstart, int N, int G) {
    int i = blockIdx.x * 256 + threadIdx.x;
    if (i >= N) return;
    int b = batch[i];
    if (i == 0) {
        for (int g = 0; g <= b; ++g) gstart[g] = 0;
    } else {
        int p = batch[i - 1];
        for (int g = p + 1; g <= b; ++g) gstart[g] = i;
    }
    if (i == N - 1) {
        for (int g = b + 1; g <= G; ++g) gstart[g] = N;
    }
}

// ---------------- CSR build (in-place in rp) ----------------
__global__ void k_count(const int* __restrict__ tgt, int* rp, int E) {
    int e = blockIdx.x * 256 + threadIdx.x;
    if (e < E) atomicAdd(&rp[tgt[e]], 1);
}

__global__ void k_dinv(const int* __restrict__ cnt, float* __restrict__ dinv, int N) {
    int i = blockIdx.x * 256 + threadIdx.x;
    if (i < N) dinv[i] = rsqrtf((float)cnt[i] + 1.f);
}

__global__ void k_scan1(int* __restrict__ rp, int* __restrict__ bsum, int N) {
    int t = threadIdx.x;
    int base = blockIdx.x * 1024 + t * 4;
    int v0 = 0, v1 = 0, v2 = 0, v3 = 0;
    if (base + 3 < N) {
        v0 = rp[base]; v1 = rp[base + 1]; v2 = rp[base + 2]; v3 = rp[base + 3];
    } else {
        if (base < N) v0 = rp[base];
        if (base + 1 < N) v1 = rp[base + 1];
        if (base + 2 < N) v2 = rp[base + 2];
    }
    int s = v0 + v1 + v2 + v3;
    int lane = t & 63, w = t >> 6;
    int x = s;
    for (int o = 1; o < 64; o <<= 1) {
        int y = __shfl_up(x, o, 64);
        if (lane >= o) x += y;
    }
    __shared__ int wsum[4];
    if (lane == 63) wsum[w] = x;
    __syncthreads();
    int woff = 0;
    for (int i = 0; i < w; ++i) woff += wsum[i];
    int excl = woff + x - s;
    if (base < N) rp[base] = excl;
    if (base + 1 < N) rp[base + 1] = excl + v0;
    if (base + 2 < N) rp[base + 2] = excl + v0 + v1;
    if (base + 3 < N) rp[base + 3] = excl + v0 + v1 + v2;
    if (t == 255) bsum[blockIdx.x] = wsum[0] + wsum[1] + wsum[2] + wsum[3];
}

__global__ void k_scan2(int* bsum, int nb) {
    int t = threadIdx.x;
    int s = (t < nb) ? bsum[t] : 0;
    int lane = t & 63, w = t >> 6;
    int x = s;
    for (int o = 1; o < 64; o <<= 1) {
        int y = __shfl_up(x, o, 64);
        if (lane >= o) x += y;
    }
    __shared__ int wsum[4];
    if (lane == 63) wsum[w] = x;
    __syncthreads();
    int woff = 0;
    for (int i = 0; i < w; ++i) woff += wsum[i];
    if (t < nb) bsum[t] = woff + x - s;
}

__global__ void k_scan3(int* __restrict__ rp, const int* __restrict__ bsum, int N) {
    int i = blockIdx.x * 256 + threadIdx.x;
    if (i < N) rp[i] += bsum[i >> 10];
}

// fill with per-edge norm; afterwards rp[n] = end(n), start(n) = rp[n-1]
__global__ void k_fill(const int* __restrict__ src, const int* __restrict__ tgt,
                       int* __restrict__ rp, const float* __restrict__ dinv,
                       int* __restrict__ esrc, float* __restrict__ enorm, int E) {
    int e = blockIdx.x * 256 + threadIdx.x;
    if (e < E) {
        int t = tgt[e];
        int s = src[e];
        int p = atomicAdd(&rp[t], 1);
        esrc[p] = s;
        enorm[p] = dinv[s] * dinv[t];
    }
}

// ---------------- GEMM: OUT[64 rows] <- Xin[64 rows] @ Wp^T (+cvec); OUT may equal Xin ----------------
__global__ __launch_bounds__(256, 3) void k_gemm(const u16* __restrict__ Xin,
                                                 const u16* __restrict__ W,
                                                 const float* __restrict__ cvec,
                                                 u16* __restrict__ out, int N) {
    __shared__ u16 As[64][260];
    __shared__ u16 Ws[256][36];
    int r0 = blockIdx.x * 64;
    int tid = threadIdx.x, lane = tid & 63, w = tid >> 6;
#pragma unroll
    for (int i = 0; i < 8; ++i) {
        int chunk = i * 256 + tid;
        int r = chunk >> 5, c8 = chunk & 31;
        *(short8*)&As[r][c8 * 8] = *(const short8*)&Xin[(size_t)(r0 + r) * 256 + c8 * 8];
    }
    f32x4 acc[16];
#pragma unroll
    for (int o = 0; o < 16; ++o) acc[o] = f32x4{0.f, 0.f, 0.f, 0.f};
    for (int k0 = 0; k0 < 256; k0 += 32) {
        __syncthreads();
#pragma unroll
        for (int i = 0; i < 4; ++i) {
            int chunk = i * 256 + tid;
            int r = chunk >> 2, c8 = chunk & 3;
            *(short8*)&Ws[r][c8 * 8] = *(const short8*)&W[(size_t)r * 256 + k0 + c8 * 8];
        }
        __syncthreads();
        half8 af = *(const half8*)&As[w * 16 + (lane & 15)][k0 + (lane >> 4) * 8];
#pragma unroll
        for (int o = 0; o < 16; ++o) {
            half8 wf = *(const half8*)&Ws[o * 16 + (lane & 15)][(lane >> 4) * 8];
            acc[o] = __builtin_amdgcn_mfma_f32_16x16x32_f16(af, wf, acc[o], 0, 0, 0);
        }
    }
    __syncthreads();
#pragma unroll
    for (int o = 0; o < 16; ++o) {
        int col = o * 16 + (lane & 15);
        float cv = cvec ? cvec[col] : 0.f;
#pragma unroll
        for (int r = 0; r < 4; ++r) {
            int row = w * 16 + (lane >> 4) * 4 + r;
            As[row][col] = f2h(acc[o][r] + cv);
        }
    }
    __syncthreads();
#pragma unroll
    for (int i = 0; i < 8; ++i) {
        int chunk = i * 256 + tid;
        int r = chunk >> 5, c8 = chunk & 31;
        *(short8*)&out[(size_t)(r0 + r) * 256 + c8 * 8] = *(const short8*)&As[r][c8 * 8];
    }
}

// ---------------- full-width aggregation (DB tier) ----------------
template <bool RS>
__global__ __launch_bounds__(256) void k_agg(const u16* __restrict__ hw,
                                             const int* __restrict__ rp,
                                             const int* __restrict__ esrc,
                                             const float* __restrict__ enorm,
                                             const float* __restrict__ dinv,
                                             const float* __restrict__ bias,
                                             u16* __restrict__ X,
                                             float* __restrict__ stats, int N) {
    int lane = threadIdx.x & 63;
    int gw = blockIdx.x * 4 + (threadIdx.x >> 6);
    int nw = gridDim.x * 4;
    float bv[4];
#pragma unroll
    for (int j = 0; j < 4; ++j) bv[j] = bias[lane * 4 + j];
    float ss[4] = {0, 0, 0, 0}, qq[4] = {0, 0, 0, 0};
    for (int n = gw; n < N; n += nw) {
        int end = rp[n];
        int start = n ? rp[n - 1] : 0;
        float dn = dinv[n];
        u16x4 hv = *(const u16x4*)&hw[(size_t)n * 256 + lane * 4];
        float a[4];
#pragma unroll
        for (int j = 0; j < 4; ++j) a[j] = h2f(hv[j]) * dn * dn + bv[j];
        for (int j = start; j < end; ++j) {
            int s = esrc[j];
            float nr = enorm[j];
            u16x4 v = *(const u16x4*)&hw[(size_t)s * 256 + lane * 4];
#pragma unroll
            for (int jj = 0; jj < 4; ++jj) a[jj] += h2f(v[jj]) * nr;
        }
        u16x4 o;
#pragma unroll
        for (int j = 0; j < 4; ++j) {
            if (RS) {
                a[j] = fmaxf(a[j], 0.f);
                ss[j] += a[j];
                qq[j] += a[j] * a[j];
            }
            o[j] = f2h(a[j]);
        }
        *(u16x4*)&X[(size_t)n * 256 + lane * 4] = o;
    }
    if (RS) {
        __shared__ float sh[512];
        int t = threadIdx.x;
        sh[t] = 0.f;
        sh[t + 256] = 0.f;
        __syncthreads();
#pragma unroll
        for (int j = 0; j < 4; ++j) {
            atomicAdd(&sh[lane * 4 + j], ss[j]);
            atomicAdd(&sh[256 + lane * 4 + j], qq[j]);
        }
        __syncthreads();
        atomicAdd(&stats[t], sh[t]);
        atomicAdd(&stats[t + 256], sh[t + 256]);
    }
}

// ---------------- half snapshot copy ----------------
__global__ void k_copyh(const u16* __restrict__ X, u16* __restrict__ Qh, int h, int N) {
    int i = blockIdx.x * 256 + threadIdx.x;
    if (i >= N * 16) return;
    int n = i >> 4, c8 = (i & 15) * 8;
    *(short8*)&Qh[(size_t)n * 128 + c8] = *(const short8*)&X[(size_t)n * 256 + h * 128 + c8];
}

// ---------------- half aggregation: 2 nodes per wave (32-lane sub-waves) ----------------
template <bool RS>
__global__ __launch_bounds__(256) void k_aggh(const u16* __restrict__ Qh,
                                              const int* __restrict__ rp,
                                              const int* __restrict__ esrc,
                                              const float* __restrict__ enorm,
                                              const float* __restrict__ dinv,
                                              const float* __restrict__ bias,
                                              u16* __restrict__ X,
                                              float* __restrict__ stats, int h, int N) {
    int l = threadIdx.x & 31;
    int sw = blockIdx.x * 8 + (threadIdx.x >> 5);
    int nsw = gridDim.x * 8;
    int colBase = h * 128 + l * 4;
    float bv[4];
#pragma unroll
    for (int j = 0; j < 4; ++j) bv[j] = bias[colBase + j];
    float ss[4] = {0, 0, 0, 0}, qq[4] = {0, 0, 0, 0};
    for (int n = sw; n < N; n += nsw) {
        int end = rp[n];
        int start = n ? rp[n - 1] : 0;
        float dn = dinv[n];
        u16x4 hv = *(const u16x4*)&Qh[(size_t)n * 128 + l * 4];
        float a[4];
#pragma unroll
        for (int j = 0; j < 4; ++j) a[j] = h2f(hv[j]) * dn * dn + bv[j];
        int j = start;
        for (; j + 1 < end; j += 2) {
            int s0 = esrc[j], s1 = esrc[j + 1];
            float n0 = enorm[j], n1 = enorm[j + 1];
            u16x4 v0 = *(const u16x4*)&Qh[(size_t)s0 * 128 + l * 4];
            u16x4 v1 = *(const u16x4*)&Qh[(size_t)s1 * 128 + l * 4];
#pragma unroll
            for (int jj = 0; jj < 4; ++jj) a[jj] += h2f(v0[jj]) * n0 + h2f(v1[jj]) * n1;
        }
        if (j < end) {
            int s0 = esrc[j];
            float n0 = enorm[j];
            u16x4 v0 = *(const u16x4*)&Qh[(size_t)s0 * 128 + l * 4];
#pragma unroll
            for (int jj = 0; jj < 4; ++jj) a[jj] += h2f(v0[jj]) * n0;
        }
        u16x4 o;
#pragma unroll
        for (int jj = 0; jj < 4; ++jj) {
            if (RS) {
                a[jj] = fmaxf(a[jj], 0.f);
                ss[jj] += a[jj];
                qq[jj] += a[jj] * a[jj];
            }
            o[jj] = f2h(a[jj]);
        }
        *(u16x4*)&X[(size_t)n * 256 + colBase] = o;
    }
    if (RS) {
        __shared__ float sh[256];
        int t = threadIdx.x;
        sh[t] = 0.f;
        __syncthreads();
#pragma unroll
        for (int j = 0; j < 4; ++j) {
            atomicAdd(&sh[l * 4 + j], ss[j]);
            atomicAdd(&sh[128 + l * 4 + j], qq[j]);
        }
        __syncthreads();
        if (t < 128)
            atomicAdd(&stats[h * 128 + t], sh[t]);
        else
            atomicAdd(&stats[256 + h * 128 + (t - 128)], sh[t]);
    }
}

// ---------------- Q-path: quarter snapshot + aggregation (lowest tier) ----------------
__global__ void k_copycol(const u16* __restrict__ X, u16* __restrict__ Q, int q, int N) {
    int i = blockIdx.x * 256 + threadIdx.x;
    if (i >= N * 16) return;
    int n = i >> 4, c4 = (i & 15) * 4;
    *(u16x4*)&Q[(size_t)n * 64 + c4] = *(const u16x4*)&X[(size_t)n * 256 + q * 64 + c4];
}

template <bool RS>
__global__ __launch_bounds__(256) void k_aggq(const u16* __restrict__ Q,
                                              const int* __restrict__ rp,
                                              const int* __restrict__ esrc,
                                              const float* __restrict__ enorm,
                                              const float* __restrict__ dinv,
                                              const float* __restrict__ bias,
                                              u16* __restrict__ X,
                                              float* __restrict__ stats, int q, int N) {
    int lane = threadIdx.x & 63;
    int gw = blockIdx.x * 4 + (threadIdx.x >> 6);
    int nw = gridDim.x * 4;
    int col = q * 64 + lane;
    float bv = bias[col];
    float ss = 0.f, qq = 0.f;
    for (int n = gw; n < N; n += nw) {
        int end = rp[n];
        int start = n ? rp[n - 1] : 0;
        float dn = dinv[n];
        float a = h2f(Q[(size_t)n * 64 + lane]) * dn * dn + bv;
        for (int j = start; j < end; ++j) {
            int s = esrc[j];
            a += h2f(Q[(size_t)s * 64 + lane]) * enorm[j];
        }
        if (RS) {
            a = fmaxf(a, 0.f);
            ss += a;
            qq += a * a;
        }
        X[(size_t)n * 256 + col] = f2h(a);
    }
    if (RS) {
        __shared__ float sh[128];
        int t = threadIdx.x;
        if (t < 128) sh[t] = 0.f;
        __syncthreads();
        atomicAdd(&sh[lane], ss);
        atomicAdd(&sh[64 + lane], qq);
        __syncthreads();
        if (t < 64) {
            atomicAdd(&stats[col], sh[lane]);
            atomicAdd(&stats[256 + col], sh[64 + lane]);
        }
    }
}

__global__ void k_bnparam(const float* __restrict__ stats, const float* __restrict__ gamma,
                          const float* __restrict__ beta, float* __restrict__ st, int N) {
    int d = threadIdx.x;
    float inv = 1.f / (float)N;
    float mu = stats[d] * inv;
    float var = fmaxf(stats[256 + d] * inv - mu * mu, 0.f);
    float sc = gamma[d] * rsqrtf(var + 1e-5f);
    st[d] = sc;
    st[256 + d] = beta[d] - mu * sc;
}

__global__ void k_fold(const float* __restrict__ W, const float* __restrict__ st,
                       u16* __restrict__ Wp, float* __restrict__ cvec) {
    __shared__ float red[256];
    int o = blockIdx.x, k = threadIdx.x;
    float w = W[o * 256 + k];
    Wp[o * 256 + k] = f2h(w * st[k]);
    red[k] = w * st[256 + k];
    __syncthreads();
    for (int s = 128; s > 0; s >>= 1) {
        if (k < s) red[k] += red[k + s];
        __syncthreads();
    }
    if (k == 0) cvec[o] = red[0];
}

// ---------------- set2set GEMM: C[M,O](f16) = A[M,K](f16) @ W[O,K](f16)^T + cvec ----------------
__global__ __launch_bounds__(256, 2) void k_gemmf(const u16* __restrict__ A,
                                                  const u16* __restrict__ W,
                                                  const float* __restrict__ cvec,
                                                  u16* __restrict__ C, int M, int K, int O) {
    const int PAD = 8;
    __shared__ u16 As[128][64 + PAD];
    __shared__ u16 Ws[128][64 + PAD];
    int tM = blockIdx.x, tO = blockIdx.y;
    int tid = threadIdx.x;
    int lane = tid & 63, wid = tid >> 6;
    int wM = wid & 1, wO = wid >> 1;
    f32x4 acc[4][4] = {};
    size_t rowA0 = (size_t)tM * 128, rowW0 = (size_t)tO * 128;
    for (int k0 = 0; k0 < K; k0 += 64) {
#pragma unroll
        for (int i = 0; i < 4; ++i) {
            int chunk = tid + i * 256;
            int r = chunk >> 3, c16 = chunk & 7;
            *(short8*)&As[r][c16 * 8] = *(const short8*)&A[(rowA0 + r) * K + k0 + c16 * 8];
            *(short8*)&Ws[r][c16 * 8] = *(const short8*)&W[(rowW0 + r) * K + k0 + c16 * 8];
        }
        __syncthreads();
#pragma unroll
        for (int ks = 0; ks < 2; ++ks) {
            half8 af[4], wf[4];
#pragma unroll
            for (int m = 0; m < 4; ++m)
                af[m] = *(const half8*)&As[wM * 64 + m * 16 + (lane & 15)][ks * 32 + (lane >> 4) * 8];
#pragma unroll
            for (int o = 0; o < 4; ++o)
                wf[o] = *(const half8*)&Ws[wO * 64 + o * 16 + (lane & 15)][ks * 32 + (lane >> 4) * 8];
#pragma unroll
            for (int m = 0; m < 4; ++m)
#pragma unroll
                for (int o = 0; o < 4; ++o)
                    acc[m][o] = __builtin_amdgcn_mfma_f32_16x16x32_f16(af[m], wf[o], acc[m][o], 0, 0, 0);
        }
        __syncthreads();
    }
#pragma unroll
    for (int m = 0; m < 4; ++m) {
        int R0 = tM * 128 + wM * 64 + m * 16 + (lane >> 4) * 4;
#pragma unroll
        for (int o = 0; o < 4; ++o) {
            int Cc = tO * 128 + wO * 64 + o * 16 + (lane & 15);
            float cv = cvec[Cc];
#pragma unroll
            for (int r = 0; r < 4; ++r)
                C[(size_t)(R0 + r) * O + Cc] = f2h(acc[m][o][r] + cv);
        }
    }
}

// ---------------- set2set pieces ----------------
__global__ void k_wcat(const float* __restrict__ Wi, const float* __restrict__ Wh,
                       const float* __restrict__ bi, const float* __restrict__ bh,
                       u16* __restrict__ Wcat, float* __restrict__ bcat) {
    int o = blockIdx.x;
    int t = threadIdx.x;
    for (int c = t; c < 512; c += 256) Wcat[(size_t)o * 768 + c] = f2h(Wi[(size_t)o * 512 + c]);
    if (t < 256) Wcat[(size_t)o * 768 + 512 + t] = f2h(Wh[(size_t)o * 256 + t]);
    if (t == 0) bcat[o] = bi[o] + bh[o];
}

__global__ void k_lstm(const u16* __restrict__ gates, float* __restrict__ cs,
                       float* __restrict__ hsb, u16* __restrict__ qsh, int G) {
    int idx = blockIdx.x * 256 + threadIdx.x;
    if (idx >= G * 256) return;
    int g = idx >> 8, d = idx & 255;
    const u16* gt = &gates[(size_t)g * 1024];
    float gi = h2f(gt[d]), gf = h2f(gt[256 + d]), gg = h2f(gt[512 + d]), go = h2f(gt[768 + d]);
    float c = sigf(gf) * cs[idx] + sigf(gi) * tanhf(gg);
    float hh = sigf(go) * tanhf(c);
    cs[idx] = c;
    hsb[idx] = hh;
    u16 hb = f2h(hh);
    qsh[(size_t)g * 768 + d] = hb;
    qsh[(size_t)g * 768 + 512 + d] = hb;
}

// ---------------- attention: one wave per graph, no LDS, no syncthreads ----------------
__global__ __launch_bounds__(256) void k_attn2(const u16* __restrict__ h3,
                                               const float* __restrict__ hs,
                                               const int* __restrict__ gstart,
                                               u16* __restrict__ qsh, int G) {
    int wid = threadIdx.x >> 6, lane = threadIdx.x & 63;
    int g = blockIdx.x * 4 + wid;
    if (g >= G) return;
    int start = gstart[g], end = gstart[g + 1];

    f32x4 q = *(const f32x4*)&hs[(size_t)g * 256 + lane * 4];
    float m = -INFINITY, z = 0.f;
    float r0a = 0.f, r1a = 0.f, r2a = 0.f, r3a = 0.f;

    for (int c0 = start; c0 < end; c0 += 256) {
        int cn = min(256, end - c0);
        float e0 = 0.f, e1 = 0.f, e2 = 0.f, e3 = 0.f;
        float mc = m;

        auto pass1 = [&](int rr, float& ev) {
            int b = c0 + rr * 64;
            int nr = min(64, end - b);
            for (int ii = 0; ii < nr; ++ii) {
                u16x4 hv = *(const u16x4*)&h3[(size_t)(b + ii) * 256 + lane * 4];
                float e = h2f(hv[0]) * q[0] + h2f(hv[1]) * q[1] + h2f(hv[2]) * q[2] + h2f(hv[3]) * q[3];
                e += __shfl_xor(e, 32, 64);
                e += __shfl_xor(e, 16, 64);
                e += __shfl_xor(e, 8, 64);
                e += __shfl_xor(e, 4, 64);
                e += __shfl_xor(e, 2, 64);
                e += __shfl_xor(e, 1, 64);
                if (lane == ii) ev = e;
                mc = fmaxf(mc, e);
            }
        };
        pass1(0, e0);
        pass1(1, e1);
        pass1(2, e2);
        pass1(3, e3);

        float rf = (m == -INFINITY) ? 0.f : expf(m - mc);
        float zc = 0.f;
        e0 = (lane < cn) ? expf(e0 - mc) : 0.f;
        zc += e0;
        e1 = (64 + lane < cn) ? expf(e1 - mc) : 0.f;
        zc += e1;
        e2 = (128 + lane < cn) ? expf(e2 - mc) : 0.f;
        zc += e2;
        e3 = (192 + lane < cn) ? expf(e3 - mc) : 0.f;
        zc += e3;
        zc += __shfl_xor(zc, 32, 64);
        zc += __shfl_xor(zc, 16, 64);
        zc += __shfl_xor(zc, 8, 64);
        zc += __shfl_xor(zc, 4, 64);
        zc += __shfl_xor(zc, 2, 64);
        zc += __shfl_xor(zc, 1, 64);
        z = z * rf + zc;
        r0a *= rf; r1a *= rf; r2a *= rf; r3a *= rf;

        auto pass2 = [&](int rr, float ev) {
            int b = c0 + rr * 64;
            int nr = min(64, end - b);
            for (int ii = 0; ii < nr; ++ii) {
                float w = __shfl(ev, ii, 64);
                u16x4 hv = *(const u16x4*)&h3[(size_t)(b + ii) * 256 + lane * 4];
                r0a += w * h2f(hv[0]);
                r1a += w * h2f(hv[1]);
                r2a += w * h2f(hv[2]);
                r3a += w * h2f(hv[3]);
            }
        };
        pass2(0, e0);
        pass2(1, e1);
        pass2(2, e2);
        pass2(3, e3);
        m = mc;
    }
    float inv = (end > start) ? 1.f / fmaxf(z, 1e-30f) : 0.f;
    u16x4 o;
    o[0] = f2h(r0a * inv);
    o[1] = f2h(r1a * inv);
    o[2] = f2h(r2a * inv);
    o[3] = f2h(r3a * inv);
    *(u16x4*)&qsh[(size_t)g * 768 + 256 + lane * 4] = o;
}

// lin1/lin2 compose
__global__ void k_wfold(const float* __restrict__ l1W, const float* __restrict__ l1b,
                        const float* __restrict__ l2W, const float* __restrict__ l2b,
                        float* __restrict__ weff) {
    int c = blockIdx.x * 256 + threadIdx.x;
    if (c < 512) {
        float s = 0.f;
        for (int t = 0; t < 128; ++t) s += l2W[t] * l1W[(size_t)t * 512 + c];
        weff[c] = s;
    }
    if (c == 0) {
        float b = l2b[0];
        for (int t = 0; t < 128; ++t) b += l2W[t] * l1b[t];
        weff[512] = b;
    }
}

__global__ __launch_bounds__(256) void k_final2(const u16* __restrict__ qsh,
                                                const float* __restrict__ weff,
                                                float* __restrict__ out, int G) {
    __shared__ float wsm[513];
    int tid = threadIdx.x;
    for (int j = tid; j < 513; j += 256) wsm[j] = weff[j];
    __syncthreads();
    int g = blockIdx.x * 4 + (tid >> 6);
    int lane = tid & 63;
    if (g >= G) return;
    const u16* qp = &qsh[(size_t)g * 768];
    float s = 0.f;
#pragma unroll
    for (int j = 0; j < 8; ++j) s += h2f(qp[lane * 8 + j]) * wsm[lane * 8 + j];
    for (int off = 32; off; off >>= 1) s += __shfl_xor(s, off, 64);
    if (lane == 0) out[g] = sigf(s + wsm[512]);
}

// ---------------- host ----------------
extern "C" void kernel_launch(void* const* d_in, const int* in_sizes, int n_in,
                              void* d_out, int out_size, void* d_ws, size_t ws_size,
                              hipStream_t stream) {
    const int* x = (const int*)d_in[0];
    const int* ei = (const int*)d_in[1];
    const int* batch = (const int*)d_in[2];
    const float* atom_emb = (const float*)d_in[4];
    const float* W1 = (const float*)d_in[5];
    const float* b1 = (const float*)d_in[6];
    const float* W2 = (const float*)d_in[7];
    const float* b2 = (const float*)d_in[8];
    const float* W3 = (const float*)d_in[9];
    const float* b3 = (const float*)d_in[10];
    const float* gamma = (const float*)d_in[11];
    const float* beta = (const float*)d_in[12];
    const float* Wi = (const float*)d_in[13];
    const float* Wh = (const float*)d_in[14];
    const float* bi = (const float*)d_in[15];
    const float* bh = (const float*)d_in[16];
    const float* l1W = (const float*)d_in[17];
    const float* l1b = (const float*)d_in[18];
    const float* l2W = (const float*)d_in[19];
    const float* l2b = (const float*)d_in[20];

    const int N = in_sizes[0] / 9;
    const int E = in_sizes[1] / 2;
    const int G = out_size;
    const int* srcp = ei;
    const int* tgtp = ei + E;

    char* ws = (char*)d_ws;
    size_t off = 0;
    auto alloc = [&](size_t bytes) -> void* {
        void* p = ws + off;
        off += (bytes + 255) & ~(size_t)255;
        return p;
    };
    u16* X = (u16*)alloc((size_t)N * 256 * 2);  // 128 MiB
    int* rp = (int*)alloc((size_t)N * 4);
    int* esrc = (int*)alloc((size_t)E * 4);
    float* enorm = (float*)alloc((size_t)E * 4);
    float* dinv = (float*)alloc((size_t)N * 4);
    int* gstart = (int*)alloc((size_t)(G + 1) * 4);
    float* stats = (float*)alloc(512 * 4);
    float* stbuf = (float*)alloc(512 * 4);
    float* cvec = (float*)alloc(256 * 4);
    u16* Wp = (u16*)alloc(256 * 256 * 2);
    int* bsum = (int*)alloc(1024 * 4);
    float* weff = (float*)alloc(513 * 4);
    size_t offR = off;

    size_t o2 = offR;
    auto alloc2 = [&](size_t bytes) -> void* {
        void* p = ws + o2;
        o2 += (bytes + 255) & ~(size_t)255;
        return p;
    };
    u16* Wcat = (u16*)alloc2((size_t)1024 * 768 * 2);
    float* bcat = (float*)alloc2(1024 * 4);
    u16* qsh = (u16*)alloc2((size_t)G * 768 * 2);
    u16* gates = (u16*)alloc2((size_t)G * 1024 * 2);
    float* hsb = (float*)alloc2((size_t)G * 256 * 4);
    float* csb = (float*)alloc2((size_t)G * 256 * 4);
    size_t s2sR = o2 - offR;

    size_t fullB = ((size_t)N * 256 * 2 + 255) & ~(size_t)255;  // 128 MiB
    size_t halfB = ((size_t)N * 128 * 2 + 255) & ~(size_t)255;  // 64 MiB
    size_t quarB = ((size_t)N * 64 * 2 + 255) & ~(size_t)255;   // 32 MiB
    auto needFor = [&](size_t b) { return offR + (b > s2sR ? b : s2sR); };
    int tier = ws_size >= needFor(fullB) ? 2 : ws_size >= needFor(halfB) ? 1
               : ws_size >= needFor(quarB) ? 0 : -1;
    if (tier < 0) {
        k_diagf<<<(G + 255) / 256, 256, 0, stream>>>((float*)d_out, G, 12345.0f);
        return;
    }
    u16* Y = (u16*)(ws + offR);  // tier-dependent scratch view

    // embed + segment starts + CSR
    k_embed<<<N / 8, 256, 0, stream>>>(x, atom_emb, X, N);
    k_gstart<<<(N + 255) / 256, 256, 0, stream>>>(batch, gstart, N, G);
    k_zero_int<<<(N + 255) / 256, 256, 0, stream>>>(rp, N);
    k_count<<<(E + 255) / 256, 256, 0, stream>>>(tgtp, rp, E);
    k_dinv<<<(N + 255) / 256, 256, 0, stream>>>(rp, dinv, N);
    int nb1 = (N + 1023) / 1024;
    k_scan1<<<nb1, 256, 0, stream>>>(rp, bsum, N);
    k_scan2<<<1, 256, 0, stream>>>(bsum, nb1);
    k_scan3<<<(N + 255) / 256, 256, 0, stream>>>(rp, bsum, N);
    k_fill<<<(E + 255) / 256, 256, 0, stream>>>(srcp, tgtp, rp, dinv, esrc, enorm, E);

    int gipb = N / 64;
    int cpb = (N * 16 + 255) / 256;
    const int AGGB = 4096;

    for (int conv = 0; conv < 3; ++conv) {
        const float* Wsrc = conv == 0 ? W1 : (conv == 1 ? W2 : W3);
        const float* bsrc = conv == 0 ? b1 : (conv == 1 ? b2 : b3);
        bool rs = conv < 2;
        if (conv == 0)
            k_cvtW<<<256, 256, 0, stream>>>(Wsrc, Wp, 65536);
        else
            k_fold<<<256, 256, 0, stream>>>(Wsrc, stbuf, Wp, cvec);
        if (rs) k_zero_f32<<<2, 256, 0, stream>>>(stats, 512);
        if (tier == 2) {
            k_gemm<<<gipb, 256, 0, stream>>>(X, Wp, conv ? cvec : nullptr, Y, N);
            if (rs)
                k_agg<true><<<AGGB, 256, 0, stream>>>(Y, rp, esrc, enorm, dinv, bsrc, X, stats, N);
            else
                k_agg<false><<<AGGB, 256, 0, stream>>>(Y, rp, esrc, enorm, dinv, bsrc, X, nullptr, N);
        } else if (tier == 1) {
            k_gemm<<<gipb, 256, 0, stream>>>(X, Wp, conv ? cvec : nullptr, X, N);
            for (int h = 0; h < 2; ++h) {
                k_copyh<<<cpb, 256, 0, stream>>>(X, Y, h, N);
                if (rs)
                    k_aggh<true><<<AGGB, 256, 0, stream>>>(Y, rp, esrc, enorm, dinv, bsrc, X, stats, h, N);
                else
                    k_aggh<false><<<AGGB, 256, 0, stream>>>(Y, rp, esrc, enorm, dinv, bsrc, X, nullptr, h, N);
            }
        } else {
            k_gemm<<<gipb, 256, 0, stream>>>(X, Wp, conv ? cvec : nullptr, X, N);
            for (int q = 0; q < 4; ++q) {
                k_copycol<<<cpb, 256, 0, stream>>>(X, Y, q, N);
                if (rs)
                    k_aggq<true><<<AGGB, 256, 0, stream>>>(Y, rp, esrc, enorm, dinv, bsrc, X, stats, q, N);
                else
                    k_aggq<false><<<AGGB, 256, 0, stream>>>(Y, rp, esrc, enorm, dinv, bsrc, X, nullptr, q, N);
            }
        }
        if (rs) k_bnparam<<<1, 256, 0, stream>>>(stats, gamma, beta, stbuf, N);
    }
    // h3 now in X

    // set2set
    k_wcat<<<1024, 256, 0, stream>>>(Wi, Wh, bi, bh, Wcat, bcat);
    k_zero_u16<<<(G * 768 + 255) / 256, 256, 0, stream>>>(qsh, G * 768);
    k_zero_f32<<<(G * 256 + 255) / 256, 256, 0, stream>>>(csb, G * 256);
    dim3 ggates(G / 128, 8);
    for (int s = 0; s < 4; ++s) {
        k_gemmf<<<ggates, 256, 0, stream>>>(qsh, Wcat, bcat, gates, G, 768, 1024);
        k_lstm<<<(G * 256 + 255) / 256, 256, 0, stream>>>(gates, csb, hsb, qsh, G);
        k_attn2<<<(G + 3) / 4, 256, 0, stream>>>(X, hsb, gstart, qsh, G);
    }
    k_wfold<<<2, 256, 0, stream>>>(l1W, l1b, l2W, l2b, weff);
    k_final2<<<(G + 3) / 4, 256, 0, stream>>>(qsh, weff, (float*)d_out, G);
}

// Round 11
// 1506.589 us; speedup vs baseline: 2.0577x; 1.0501x over previous
//
#include <hip/hip_runtime.h>
#include <hip/hip_bf16.h>
#include <math.h>

using u16 = unsigned short;
typedef __attribute__((ext_vector_type(8))) short short8;
typedef __attribute__((ext_vector_type(8))) _Float16 half8;
typedef __attribute__((ext_vector_type(4))) float f32x4;
typedef __attribute__((ext_vector_type(4))) u16 u16x4;

__device__ __constant__ int c_OFF[9] = {0, 119, 123, 135, 147, 157, 163, 169, 171};

__device__ __forceinline__ float h2f(u16 u) {
    _Float16 h;
    __builtin_memcpy(&h, &u, 2);
    return (float)h;
}
__device__ __forceinline__ u16 f2h(float f) {
    _Float16 h = (_Float16)f;
    u16 u;
    __builtin_memcpy(&u, &h, 2);
    return u;
}
__device__ __forceinline__ float sigf(float x) { return 1.f / (1.f + expf(-x)); }

// ---------------- diagnostics ----------------
__global__ void k_diagf(float* out, int G, float val) {
    int i = blockIdx.x * 256 + threadIdx.x;
    if (i < G) out[i] = val;
}

// ---------------- zero helpers ----------------
__global__ void k_zero_f32(float* p, int n) {
    int i = blockIdx.x * 256 + threadIdx.x;
    if (i < n) p[i] = 0.f;
}
__global__ void k_zero_u16(u16* p, int n) {
    int i = blockIdx.x * 256 + threadIdx.x;
    if (i < n) p[i] = 0;
}
__global__ void k_zero_int(int* p, int n) {
    int i = blockIdx.x * 256 + threadIdx.x;
    if (i < n) p[i] = 0;
}

// ---------------- fp32 -> fp16 convert ----------------
__global__ void k_cvtW(const float* __restrict__ src, u16* __restrict__ dst, int n) {
    int i = blockIdx.x * 256 + threadIdx.x;
    if (i < n) dst[i] = f2h(src[i]);
}

// ---------------- atom encoder: 8 nodes/block, 8 cols/thread, vectorized ----------------
__global__ __launch_bounds__(256) void k_embed(const int* __restrict__ x,
                                               const float* __restrict__ emb,
                                               u16* __restrict__ out, int N) {
    __shared__ int rows[72];
    int nb = blockIdx.x * 8;
    int tid = threadIdx.x;
    if (tid < 72) rows[tid] = x[(size_t)nb * 9 + tid] + c_OFF[tid % 9];
    __syncthreads();
    int ln = tid >> 5;
    int c8 = (tid & 31) * 8;
    float s0 = 0.f, s1 = 0.f, s2 = 0.f, s3 = 0.f, s4 = 0.f, s5 = 0.f, s6 = 0.f, s7 = 0.f;
#pragma unroll
    for (int c = 0; c < 9; ++c) {
        int r = rows[ln * 9 + c];
        f32x4 a = *(const f32x4*)&emb[r * 256 + c8];
        f32x4 b = *(const f32x4*)&emb[r * 256 + c8 + 4];
        s0 += a[0]; s1 += a[1]; s2 += a[2]; s3 += a[3];
        s4 += b[0]; s5 += b[1]; s6 += b[2]; s7 += b[3];
    }
    short8 o;
    o[0] = (short)f2h(s0); o[1] = (short)f2h(s1); o[2] = (short)f2h(s2); o[3] = (short)f2h(s3);
    o[4] = (short)f2h(s4); o[5] = (short)f2h(s5); o[6] = (short)f2h(s6); o[7] = (short)f2h(s7);
    *(short8*)&out[(size_t)(nb + ln) * 256 + c8] = o;
}

// ---------------- graph segment starts from sorted batch ----------------
__global__ void k_gstart(const int* __restrict__ batch, int* __restrict__ gstart, int N, int G) {
    int i = blockIdx.x * 256 + threadIdx.x;
    if (i >= N) return;
    int b = batch[i];
    if (i == 0) {
        for (int g = 0; g <= b; ++g) gstart[g] = 0;
    } else {
        int p = batch[i - 1];
        for (int g = p + 1; g <= b; ++g) gstart[g] = i;
    }
    if (i == N - 1) {
        for (int g = b + 1; g <= G; ++g) gstart[g] = N;
    }
}

// ---------------- CSR build (in-place in rp) ----------------
__global__ void k_count(const int* __restrict__ tgt, int* rp, int E) {
    int e = blockIdx.x * 256 + threadIdx.x;
    if (e < E) atomicAdd(&rp[tgt[e]], 1);
}

__global__ void k_dinv(const int* __restrict__ cnt, float* __restrict__ dinv, int N) {
    int i = blockIdx.x * 256 + threadIdx.x;
    if (i < N) dinv[i] = rsqrtf((float)cnt[i] + 1.f);
}

__global__ void k_scan1(int* __restrict__ rp, int* __restrict__ bsum, int N) {
    int t = threadIdx.x;
    int base = blockIdx.x * 1024 + t * 4;
    int v0 = 0, v1 = 0, v2 = 0, v3 = 0;
    if (base + 3 < N) {
        v0 = rp[base]; v1 = rp[base + 1]; v2 = rp[base + 2]; v3 = rp[base + 3];
    } else {
        if (base < N) v0 = rp[base];
        if (base + 1 < N) v1 = rp[base + 1];
        if (base + 2 < N) v2 = rp[base + 2];
    }
    int s = v0 + v1 + v2 + v3;
    int lane = t & 63, w = t >> 6;
    int x = s;
    for (int o = 1; o < 64; o <<= 1) {
        int y = __shfl_up(x, o, 64);
        if (lane >= o) x += y;
    }
    __shared__ int wsum[4];
    if (lane == 63) wsum[w] = x;
    __syncthreads();
    int woff = 0;
    for (int i = 0; i < w; ++i) woff += wsum[i];
    int excl = woff + x - s;
    if (base < N) rp[base] = excl;
    if (base + 1 < N) rp[base + 1] = excl + v0;
    if (base + 2 < N) rp[base + 2] = excl + v0 + v1;
    if (base + 3 < N) rp[base + 3] = excl + v0 + v1 + v2;
    if (t == 255) bsum[blockIdx.x] = wsum[0] + wsum[1] + wsum[2] + wsum[3];
}

__global__ void k_scan2(int* bsum, int nb) {
    int t = threadIdx.x;
    int s = (t < nb) ? bsum[t] : 0;
    int lane = t & 63, w = t >> 6;
    int x = s;
    for (int o = 1; o < 64; o <<= 1) {
        int y = __shfl_up(x, o, 64);
        if (lane >= o) x += y;
    }
    __shared__ int wsum[4];
    if (lane == 63) wsum[w] = x;
    __syncthreads();
    int woff = 0;
    for (int i = 0; i < w; ++i) woff += wsum[i];
    if (t < nb) bsum[t] = woff + x - s;
}

__global__ void k_scan3(int* __restrict__ rp, const int* __restrict__ bsum, int N) {
    int i = blockIdx.x * 256 + threadIdx.x;
    if (i < N) rp[i] += bsum[i >> 10];
}

// fill with packed (src, norm); afterwards rp[n] = end(n), start(n) = rp[n-1]
__global__ void k_fill(const int* __restrict__ src, const int* __restrict__ tgt,
                       int* __restrict__ rp, const float* __restrict__ dinv,
                       int2* __restrict__ est, int E) {
    int e = blockIdx.x * 256 + threadIdx.x;
    if (e < E) {
        int t = tgt[e];
        int s = src[e];
        int p = atomicAdd(&rp[t], 1);
        est[p] = make_int2(s, __float_as_int(dinv[s] * dinv[t]));
    }
}

// ---------------- GEMM: out[64 rows of X] <- A(from two half-buffers) @ Wp^T (+cvec) ----------------
// A-tile fully staged in LDS before any write -> in-place safe.
__global__ __launch_bounds__(256, 3) void k_gemm(const u16* __restrict__ p0, int rs0,
                                                 const u16* __restrict__ p1, int rs1,
                                                 const u16* __restrict__ W,
                                                 const float* __restrict__ cvec,
                                                 u16* __restrict__ out, int N) {
    __shared__ u16 As[64][260];
    __shared__ u16 Ws[256][36];
    int r0 = blockIdx.x * 64;
    int tid = threadIdx.x, lane = tid & 63, w = tid >> 6;
#pragma unroll
    for (int i = 0; i < 8; ++i) {
        int chunk = i * 256 + tid;
        int r = chunk >> 5, c8 = chunk & 31;
        const u16* sp = (c8 < 16) ? &p0[(size_t)(r0 + r) * rs0 + c8 * 8]
                                  : &p1[(size_t)(r0 + r) * rs1 + (c8 - 16) * 8];
        *(short8*)&As[r][c8 * 8] = *(const short8*)sp;
    }
    f32x4 acc[16];
#pragma unroll
    for (int o = 0; o < 16; ++o) acc[o] = f32x4{0.f, 0.f, 0.f, 0.f};
    for (int k0 = 0; k0 < 256; k0 += 32) {
        __syncthreads();
#pragma unroll
        for (int i = 0; i < 4; ++i) {
            int chunk = i * 256 + tid;
            int r = chunk >> 2, c8 = chunk & 3;
            *(short8*)&Ws[r][c8 * 8] = *(const short8*)&W[(size_t)r * 256 + k0 + c8 * 8];
        }
        __syncthreads();
        half8 af = *(const half8*)&As[w * 16 + (lane & 15)][k0 + (lane >> 4) * 8];
#pragma unroll
        for (int o = 0; o < 16; ++o) {
            half8 wf = *(const half8*)&Ws[o * 16 + (lane & 15)][(lane >> 4) * 8];
            acc[o] = __builtin_amdgcn_mfma_f32_16x16x32_f16(af, wf, acc[o], 0, 0, 0);
        }
    }
    __syncthreads();
#pragma unroll
    for (int o = 0; o < 16; ++o) {
        int col = o * 16 + (lane & 15);
        float cv = cvec ? cvec[col] : 0.f;
#pragma unroll
        for (int r = 0; r < 4; ++r) {
            int row = w * 16 + (lane >> 4) * 4 + r;
            As[row][col] = f2h(acc[o][r] + cv);
        }
    }
    __syncthreads();
#pragma unroll
    for (int i = 0; i < 8; ++i) {
        int chunk = i * 256 + tid;
        int r = chunk >> 5, c8 = chunk & 31;
        *(short8*)&out[(size_t)(r0 + r) * 256 + c8 * 8] = *(const short8*)&As[r][c8 * 8];
    }
}

// ---------------- half aggregation: 16-lane sub-waves, packed edges ----------------
// dst/src pointers carry the column offset; strides passed explicitly.
template <bool RS>
__global__ __launch_bounds__(256) void k_aggh(const u16* __restrict__ src, int srs,
                                              u16* __restrict__ dst, int drs,
                                              const int* __restrict__ rp,
                                              const int2* __restrict__ est,
                                              const float* __restrict__ dinv,
                                              const float* __restrict__ biasH,
                                              float* __restrict__ statS,
                                              float* __restrict__ statQ, int N) {
    int l = threadIdx.x & 15;
    int sub = blockIdx.x * 16 + (threadIdx.x >> 4);
    int nsub = gridDim.x * 16;
    float bv[8];
#pragma unroll
    for (int k = 0; k < 8; ++k) bv[k] = biasH[l * 8 + k];
    float ss[8] = {}, qq[8] = {};
    for (int n = sub; n < N; n += nsub) {
        int start = n ? rp[n - 1] : 0;
        int end = rp[n];
        float dn = dinv[n];
        short8 hv = *(const short8*)&src[(size_t)n * srs + l * 8];
        float a[8];
#pragma unroll
        for (int k = 0; k < 8; ++k) a[k] = h2f((u16)hv[k]) * dn * dn + bv[k];
        int j = start;
        for (; j + 1 < end; j += 2) {
            int2 e0 = est[j], e1 = est[j + 1];
            float n0 = __int_as_float(e0.y), n1 = __int_as_float(e1.y);
            short8 v0 = *(const short8*)&src[(size_t)e0.x * srs + l * 8];
            short8 v1 = *(const short8*)&src[(size_t)e1.x * srs + l * 8];
#pragma unroll
            for (int k = 0; k < 8; ++k) a[k] += h2f((u16)v0[k]) * n0 + h2f((u16)v1[k]) * n1;
        }
        if (j < end) {
            int2 e0 = est[j];
            float n0 = __int_as_float(e0.y);
            short8 v0 = *(const short8*)&src[(size_t)e0.x * srs + l * 8];
#pragma unroll
            for (int k = 0; k < 8; ++k) a[k] += h2f((u16)v0[k]) * n0;
        }
        short8 o;
#pragma unroll
        for (int k = 0; k < 8; ++k) {
            if (RS) {
                a[k] = fmaxf(a[k], 0.f);
                ss[k] += a[k];
                qq[k] += a[k] * a[k];
            }
            o[k] = (short)f2h(a[k]);
        }
        *(short8*)&dst[(size_t)n * drs + l * 8] = o;
    }
    if (RS) {
        __shared__ float sh[256];
        int t = threadIdx.x;
        sh[t] = 0.f;
        __syncthreads();
#pragma unroll
        for (int k = 0; k < 8; ++k) {
            atomicAdd(&sh[l * 8 + k], ss[k]);
            atomicAdd(&sh[128 + l * 8 + k], qq[k]);
        }
        __syncthreads();
        if (t < 128)
            atomicAdd(&statS[t], sh[t]);
        else
            atomicAdd(&statQ[t - 128], sh[t]);
    }
}

// ---------------- half snapshot copy: X-half (stride 256, ptr carries offset) -> Y (stride 128) ----------------
__global__ void k_copyh(const u16* __restrict__ src, u16* __restrict__ dst, int N) {
    int i = blockIdx.x * 256 + threadIdx.x;
    if (i >= N * 16) return;
    int n = i >> 4, c8 = (i & 15) * 8;
    *(short8*)&dst[(size_t)n * 128 + c8] = *(const short8*)&src[(size_t)n * 256 + c8];
}

__global__ void k_bnparam(const float* __restrict__ stats, const float* __restrict__ gamma,
                          const float* __restrict__ beta, float* __restrict__ st, int N) {
    int d = threadIdx.x;
    float inv = 1.f / (float)N;
    float mu = stats[d] * inv;
    float var = fmaxf(stats[256 + d] * inv - mu * mu, 0.f);
    float sc = gamma[d] * rsqrtf(var + 1e-5f);
    st[d] = sc;
    st[256 + d] = beta[d] - mu * sc;
}

__global__ void k_fold(const float* __restrict__ W, const float* __restrict__ st,
                       u16* __restrict__ Wp, float* __restrict__ cvec) {
    __shared__ float red[256];
    int o = blockIdx.x, k = threadIdx.x;
    float w = W[o * 256 + k];
    Wp[o * 256 + k] = f2h(w * st[k]);
    red[k] = w * st[256 + k];
    __syncthreads();
    for (int s = 128; s > 0; s >>= 1) {
        if (k < s) red[k] += red[k + s];
        __syncthreads();
    }
    if (k == 0) cvec[o] = red[0];
}

// ---------------- set2set GEMM: C[M,O](f16) = A[M,K](f16) @ W[O,K](f16)^T + cvec ----------------
__global__ __launch_bounds__(256, 2) void k_gemmf(const u16* __restrict__ A,
                                                  const u16* __restrict__ W,
                                                  const float* __restrict__ cvec,
                                                  u16* __restrict__ C, int M, int K, int O) {
    const int PAD = 8;
    __shared__ u16 As[128][64 + PAD];
    __shared__ u16 Ws[128][64 + PAD];
    int tM = blockIdx.x, tO = blockIdx.y;
    int tid = threadIdx.x;
    int lane = tid & 63, wid = tid >> 6;
    int wM = wid & 1, wO = wid >> 1;
    f32x4 acc[4][4] = {};
    size_t rowA0 = (size_t)tM * 128, rowW0 = (size_t)tO * 128;
    for (int k0 = 0; k0 < K; k0 += 64) {
#pragma unroll
        for (int i = 0; i < 4; ++i) {
            int chunk = tid + i * 256;
            int r = chunk >> 3, c16 = chunk & 7;
            *(short8*)&As[r][c16 * 8] = *(const short8*)&A[(rowA0 + r) * K + k0 + c16 * 8];
            *(short8*)&Ws[r][c16 * 8] = *(const short8*)&W[(rowW0 + r) * K + k0 + c16 * 8];
        }
        __syncthreads();
#pragma unroll
        for (int ks = 0; ks < 2; ++ks) {
            half8 af[4], wf[4];
#pragma unroll
            for (int m = 0; m < 4; ++m)
                af[m] = *(const half8*)&As[wM * 64 + m * 16 + (lane & 15)][ks * 32 + (lane >> 4) * 8];
#pragma unroll
            for (int o = 0; o < 4; ++o)
                wf[o] = *(const half8*)&Ws[wO * 64 + o * 16 + (lane & 15)][ks * 32 + (lane >> 4) * 8];
#pragma unroll
            for (int m = 0; m < 4; ++m)
#pragma unroll
                for (int o = 0; o < 4; ++o)
                    acc[m][o] = __builtin_amdgcn_mfma_f32_16x16x32_f16(af[m], wf[o], acc[m][o], 0, 0, 0);
        }
        __syncthreads();
    }
#pragma unroll
    for (int m = 0; m < 4; ++m) {
        int R0 = tM * 128 + wM * 64 + m * 16 + (lane >> 4) * 4;
#pragma unroll
        for (int o = 0; o < 4; ++o) {
            int Cc = tO * 128 + wO * 64 + o * 16 + (lane & 15);
            float cv = cvec[Cc];
#pragma unroll
            for (int r = 0; r < 4; ++r)
                C[(size_t)(R0 + r) * O + Cc] = f2h(acc[m][o][r] + cv);
        }
    }
}

// ---------------- set2set pieces ----------------
__global__ void k_wcat(const float* __restrict__ Wi, const float* __restrict__ Wh,
                       const float* __restrict__ bi, const float* __restrict__ bh,
                       u16* __restrict__ Wcat, float* __restrict__ bcat) {
    int o = blockIdx.x;
    int t = threadIdx.x;
    for (int c = t; c < 512; c += 256) Wcat[(size_t)o * 768 + c] = f2h(Wi[(size_t)o * 512 + c]);
    if (t < 256) Wcat[(size_t)o * 768 + 512 + t] = f2h(Wh[(size_t)o * 256 + t]);
    if (t == 0) bcat[o] = bi[o] + bh[o];
}

__global__ void k_lstm(const u16* __restrict__ gates, float* __restrict__ cs,
                       float* __restrict__ hsb, u16* __restrict__ qsh, int G) {
    int idx = blockIdx.x * 256 + threadIdx.x;
    if (idx >= G * 256) return;
    int g = idx >> 8, d = idx & 255;
    const u16* gt = &gates[(size_t)g * 1024];
    float gi = h2f(gt[d]), gf = h2f(gt[256 + d]), gg = h2f(gt[512 + d]), go = h2f(gt[768 + d]);
    float c = sigf(gf) * cs[idx] + sigf(gi) * tanhf(gg);
    float hh = sigf(go) * tanhf(c);
    cs[idx] = c;
    hsb[idx] = hh;
    u16 hb = f2h(hh);
    qsh[(size_t)g * 768 + d] = hb;
    qsh[(size_t)g * 768 + 512 + d] = hb;
}

// ---------------- attention: one wave per graph, no LDS, no syncthreads ----------------
__global__ __launch_bounds__(256) void k_attn2(const u16* __restrict__ h3,
                                               const float* __restrict__ hs,
                                               const int* __restrict__ gstart,
                                               u16* __restrict__ qsh, int G) {
    int wid = threadIdx.x >> 6, lane = threadIdx.x & 63;
    int g = blockIdx.x * 4 + wid;
    if (g >= G) return;
    int start = gstart[g], end = gstart[g + 1];

    f32x4 q = *(const f32x4*)&hs[(size_t)g * 256 + lane * 4];
    float m = -INFINITY, z = 0.f;
    float r0a = 0.f, r1a = 0.f, r2a = 0.f, r3a = 0.f;

    for (int c0 = start; c0 < end; c0 += 256) {
        int cn = min(256, end - c0);
        float e0 = 0.f, e1 = 0.f, e2 = 0.f, e3 = 0.f;
        float mc = m;

        auto pass1 = [&](int rr, float& ev) {
            int b = c0 + rr * 64;
            int nr = min(64, end - b);
            for (int ii = 0; ii < nr; ++ii) {
                u16x4 hv = *(const u16x4*)&h3[(size_t)(b + ii) * 256 + lane * 4];
                float e = h2f(hv[0]) * q[0] + h2f(hv[1]) * q[1] + h2f(hv[2]) * q[2] + h2f(hv[3]) * q[3];
                e += __shfl_xor(e, 32, 64);
                e += __shfl_xor(e, 16, 64);
                e += __shfl_xor(e, 8, 64);
                e += __shfl_xor(e, 4, 64);
                e += __shfl_xor(e, 2, 64);
                e += __shfl_xor(e, 1, 64);
                if (lane == ii) ev = e;
                mc = fmaxf(mc, e);
            }
        };
        pass1(0, e0);
        pass1(1, e1);
        pass1(2, e2);
        pass1(3, e3);

        float rf = (m == -INFINITY) ? 0.f : expf(m - mc);
        float zc = 0.f;
        e0 = (lane < cn) ? expf(e0 - mc) : 0.f;
        zc += e0;
        e1 = (64 + lane < cn) ? expf(e1 - mc) : 0.f;
        zc += e1;
        e2 = (128 + lane < cn) ? expf(e2 - mc) : 0.f;
        zc += e2;
        e3 = (192 + lane < cn) ? expf(e3 - mc) : 0.f;
        zc += e3;
        zc += __shfl_xor(zc, 32, 64);
        zc += __shfl_xor(zc, 16, 64);
        zc += __shfl_xor(zc, 8, 64);
        zc += __shfl_xor(zc, 4, 64);
        zc += __shfl_xor(zc, 2, 64);
        zc += __shfl_xor(zc, 1, 64);
        z = z * rf + zc;
        r0a *= rf; r1a *= rf; r2a *= rf; r3a *= rf;

        auto pass2 = [&](int rr, float ev) {
            int b = c0 + rr * 64;
            int nr = min(64, end - b);
            for (int ii = 0; ii < nr; ++ii) {
                float w = __shfl(ev, ii, 64);
                u16x4 hv = *(const u16x4*)&h3[(size_t)(b + ii) * 256 + lane * 4];
                r0a += w * h2f(hv[0]);
                r1a += w * h2f(hv[1]);
                r2a += w * h2f(hv[2]);
                r3a += w * h2f(hv[3]);
            }
        };
        pass2(0, e0);
        pass2(1, e1);
        pass2(2, e2);
        pass2(3, e3);
        m = mc;
    }
    float inv = (end > start) ? 1.f / fmaxf(z, 1e-30f) : 0.f;
    u16x4 o;
    o[0] = f2h(r0a * inv);
    o[1] = f2h(r1a * inv);
    o[2] = f2h(r2a * inv);
    o[3] = f2h(r3a * inv);
    *(u16x4*)&qsh[(size_t)g * 768 + 256 + lane * 4] = o;
}

// lin1/lin2 compose
__global__ void k_wfold(const float* __restrict__ l1W, const float* __restrict__ l1b,
                        const float* __restrict__ l2W, const float* __restrict__ l2b,
                        float* __restrict__ weff) {
    int c = blockIdx.x * 256 + threadIdx.x;
    if (c < 512) {
        float s = 0.f;
        for (int t = 0; t < 128; ++t) s += l2W[t] * l1W[(size_t)t * 512 + c];
        weff[c] = s;
    }
    if (c == 0) {
        float b = l2b[0];
        for (int t = 0; t < 128; ++t) b += l2W[t] * l1b[t];
        weff[512] = b;
    }
}

__global__ __launch_bounds__(256) void k_final2(const u16* __restrict__ qsh,
                                                const float* __restrict__ weff,
                                                float* __restrict__ out, int G) {
    __shared__ float wsm[513];
    int tid = threadIdx.x;
    for (int j = tid; j < 513; j += 256) wsm[j] = weff[j];
    __syncthreads();
    int g = blockIdx.x * 4 + (tid >> 6);
    int lane = tid & 63;
    if (g >= G) return;
    const u16* qp = &qsh[(size_t)g * 768];
    float s = 0.f;
#pragma unroll
    for (int j = 0; j < 8; ++j) s += h2f(qp[lane * 8 + j]) * wsm[lane * 8 + j];
    for (int off = 32; off; off >>= 1) s += __shfl_xor(s, off, 64);
    if (lane == 0) out[g] = sigf(s + wsm[512]);
}

// ---------------- host ----------------
extern "C" void kernel_launch(void* const* d_in, const int* in_sizes, int n_in,
                              void* d_out, int out_size, void* d_ws, size_t ws_size,
                              hipStream_t stream) {
    const int* x = (const int*)d_in[0];
    const int* ei = (const int*)d_in[1];
    const int* batch = (const int*)d_in[2];
    const float* atom_emb = (const float*)d_in[4];
    const float* W1 = (const float*)d_in[5];
    const float* b1 = (const float*)d_in[6];
    const float* W2 = (const float*)d_in[7];
    const float* b2 = (const float*)d_in[8];
    const float* W3 = (const float*)d_in[9];
    const float* b3 = (const float*)d_in[10];
    const float* gamma = (const float*)d_in[11];
    const float* beta = (const float*)d_in[12];
    const float* Wi = (const float*)d_in[13];
    const float* Wh = (const float*)d_in[14];
    const float* bi = (const float*)d_in[15];
    const float* bh = (const float*)d_in[16];
    const float* l1W = (const float*)d_in[17];
    const float* l1b = (const float*)d_in[18];
    const float* l2W = (const float*)d_in[19];
    const float* l2b = (const float*)d_in[20];

    const int N = in_sizes[0] / 9;
    const int E = in_sizes[1] / 2;
    const int G = out_size;
    const int* srcp = ei;
    const int* tgtp = ei + E;

    char* ws = (char*)d_ws;
    size_t off = 0;
    auto alloc = [&](size_t bytes) -> void* {
        void* p = ws + off;
        off += (bytes + 255) & ~(size_t)255;
        return p;
    };
    u16* X = (u16*)alloc((size_t)N * 256 * 2);  // 128 MiB
    int* rp = (int*)alloc((size_t)N * 4);
    int2* est = (int2*)alloc((size_t)E * 8);
    float* dinv = (float*)alloc((size_t)N * 4);
    int* gstart = (int*)alloc((size_t)(G + 1) * 4);
    float* stats = (float*)alloc(512 * 4);
    float* stbuf = (float*)alloc(512 * 4);
    float* cvec = (float*)alloc(256 * 4);
    u16* Wp = (u16*)alloc(256 * 256 * 2);
    int* bsum = (int*)alloc(1024 * 4);
    float* weff = (float*)alloc(513 * 4);
    size_t offR = off;

    size_t o2 = offR;
    auto alloc2 = [&](size_t bytes) -> void* {
        void* p = ws + o2;
        o2 += (bytes + 255) & ~(size_t)255;
        return p;
    };
    u16* Wcat = (u16*)alloc2((size_t)1024 * 768 * 2);
    float* bcat = (float*)alloc2(1024 * 4);
    u16* qsh = (u16*)alloc2((size_t)G * 768 * 2);
    u16* gates = (u16*)alloc2((size_t)G * 1024 * 2);
    float* hsb = (float*)alloc2((size_t)G * 256 * 4);
    float* csb = (float*)alloc2((size_t)G * 256 * 4);
    size_t s2sR = o2 - offR;

    size_t halfB = ((size_t)N * 128 * 2 + 255) & ~(size_t)255;  // 64 MiB
    size_t need = offR + (halfB > s2sR ? halfB : s2sR);
    if (ws_size < need) {
        k_diagf<<<(G + 255) / 256, 256, 0, stream>>>((float*)d_out, G, 12345.0f);
        return;
    }
    u16* Y = (u16*)(ws + offR);  // 64-MiB rotation buffer; aliased by s2s region after conv3

    // embed + segment starts + CSR
    k_embed<<<N / 8, 256, 0, stream>>>(x, atom_emb, X, N);
    k_gstart<<<(N + 255) / 256, 256, 0, stream>>>(batch, gstart, N, G);
    k_zero_int<<<(N + 255) / 256, 256, 0, stream>>>(rp, N);
    k_count<<<(E + 255) / 256, 256, 0, stream>>>(tgtp, rp, E);
    k_dinv<<<(N + 255) / 256, 256, 0, stream>>>(rp, dinv, N);
    int nb1 = (N + 1023) / 1024;
    k_scan1<<<nb1, 256, 0, stream>>>(rp, bsum, N);
    k_scan2<<<1, 256, 0, stream>>>(bsum, nb1);
    k_scan3<<<(N + 255) / 256, 256, 0, stream>>>(rp, bsum, N);
    k_fill<<<(E + 255) / 256, 256, 0, stream>>>(srcp, tgtp, rp, dinv, est, E);

    int gipb = N / 64;
    int cpb = (N * 16 + 255) / 256;
    const int AGGB = 4096;

    // Feature location state: (loc of cols 0-127, loc of cols 128-255).
    // After embed: (X+0 /256, X+128 /256).
    // conv1: GEMM -> X full; agg h0: X+0 -> Y; agg h1: X+128 -> X+0. State: (Y/128, X+0/256).
    k_cvtW<<<256, 256, 0, stream>>>(W1, Wp, 65536);
    k_zero_f32<<<2, 256, 0, stream>>>(stats, 512);
    k_gemm<<<gipb, 256, 0, stream>>>(X, 256, X + 128, 256, Wp, nullptr, X, N);
    k_aggh<true><<<AGGB, 256, 0, stream>>>(X, 256, Y, 128, rp, est, dinv, b1, stats, stats + 256, N);
    k_aggh<true><<<AGGB, 256, 0, stream>>>(X + 128, 256, X, 256, rp, est, dinv, b1 + 128, stats + 128, stats + 384, N);
    k_bnparam<<<1, 256, 0, stream>>>(stats, gamma, beta, stbuf, N);

    // conv2: GEMM reads (Y/128, X+0/256) -> X full; same rotation. State stays (Y/128, X+0/256).
    k_fold<<<256, 256, 0, stream>>>(W2, stbuf, Wp, cvec);
    k_zero_f32<<<2, 256, 0, stream>>>(stats, 512);
    k_gemm<<<gipb, 256, 0, stream>>>(Y, 128, X, 256, Wp, cvec, X, N);
    k_aggh<true><<<AGGB, 256, 0, stream>>>(X, 256, Y, 128, rp, est, dinv, b2, stats, stats + 256, N);
    k_aggh<true><<<AGGB, 256, 0, stream>>>(X + 128, 256, X, 256, rp, est, dinv, b2 + 128, stats + 128, stats + 384, N);
    k_bnparam<<<1, 256, 0, stream>>>(stats, gamma, beta, stbuf, N);

    // conv3: GEMM -> X full; snapshot path so h3 ends fully in X (Y freed for s2s).
    k_fold<<<256, 256, 0, stream>>>(W3, stbuf, Wp, cvec);
    k_gemm<<<gipb, 256, 0, stream>>>(Y, 128, X, 256, Wp, cvec, X, N);
    k_copyh<<<cpb, 256, 0, stream>>>(X, Y, N);
    k_aggh<false><<<AGGB, 256, 0, stream>>>(Y, 128, X, 256, rp, est, dinv, b3, nullptr, nullptr, N);
    k_copyh<<<cpb, 256, 0, stream>>>(X + 128, Y, N);
    k_aggh<false><<<AGGB, 256, 0, stream>>>(Y, 128, X + 128, 256, rp, est, dinv, b3 + 128, nullptr, nullptr, N);
    // h3 now fully in X

    // set2set
    k_wcat<<<1024, 256, 0, stream>>>(Wi, Wh, bi, bh, Wcat, bcat);
    k_zero_u16<<<(G * 768 + 255) / 256, 256, 0, stream>>>(qsh, G * 768);
    k_zero_f32<<<(G * 256 + 255) / 256, 256, 0, stream>>>(csb, G * 256);
    dim3 ggates(G / 128, 8);
    for (int s = 0; s < 4; ++s) {
        k_gemmf<<<ggates, 256, 0, stream>>>(qsh, Wcat, bcat, gates, G, 768, 1024);
        k_lstm<<<(G * 256 + 255) / 256, 256, 0, stream>>>(gates, csb, hsb, qsh, G);
        k_attn2<<<(G + 3) / 4, 256, 0, stream>>>(X, hsb, gstart, qsh, G);
    }
    k_wfold<<<2, 256, 0, stream>>>(l1W, l1b, l2W, l2b, weff);
    k_final2<<<(G + 3) / 4, 256, 0, stream>>>(qsh, weff, (float*)d_out, G);
}

// Round 12
// 1468.618 us; speedup vs baseline: 2.1109x; 1.0259x over previous
//
#include <hip/hip_runtime.h>
#include <hip/hip_bf16.h>
#include <math.h>

using u16 = unsigned short;
typedef __attribute__((ext_vector_type(8))) short short8;
typedef __attribute__((ext_vector_type(8))) _Float16 half8;
typedef __attribute__((ext_vector_type(4))) float f32x4;
typedef __attribute__((ext_vector_type(4))) u16 u16x4;

__device__ __constant__ int c_OFF[9] = {0, 119, 123, 135, 147, 157, 163, 169, 171};

__device__ __forceinline__ float h2f(u16 u) {
    _Float16 h;
    __builtin_memcpy(&h, &u, 2);
    return (float)h;
}
__device__ __forceinline__ u16 f2h(float f) {
    _Float16 h = (_Float16)f;
    u16 u;
    __builtin_memcpy(&u, &h, 2);
    return u;
}
__device__ __forceinline__ float sigf(float x) { return 1.f / (1.f + expf(-x)); }

// ---------------- diagnostics ----------------
__global__ void k_diagf(float* out, int G, float val) {
    int i = blockIdx.x * 256 + threadIdx.x;
    if (i < G) out[i] = val;
}

// ---------------- zero helpers ----------------
__global__ void k_zero_f32(float* p, int n) {
    int i = blockIdx.x * 256 + threadIdx.x;
    if (i < n) p[i] = 0.f;
}
__global__ void k_zero_u16(u16* p, int n) {
    int i = blockIdx.x * 256 + threadIdx.x;
    if (i < n) p[i] = 0;
}
__global__ void k_zero_int(int* p, int n) {
    int i = blockIdx.x * 256 + threadIdx.x;
    if (i < n) p[i] = 0;
}

// ---------------- fp32 -> fp16 convert ----------------
__global__ void k_cvtW(const float* __restrict__ src, u16* __restrict__ dst, int n) {
    int i = blockIdx.x * 256 + threadIdx.x;
    if (i < n) dst[i] = f2h(src[i]);
}

// ---------------- atom encoder: 8 nodes/block, 8 cols/thread, vectorized ----------------
__global__ __launch_bounds__(256) void k_embed(const int* __restrict__ x,
                                               const float* __restrict__ emb,
                                               u16* __restrict__ out, int N) {
    __shared__ int rows[72];
    int nb = blockIdx.x * 8;
    int tid = threadIdx.x;
    if (tid < 72) rows[tid] = x[(size_t)nb * 9 + tid] + c_OFF[tid % 9];
    __syncthreads();
    int ln = tid >> 5;
    int c8 = (tid & 31) * 8;
    float s0 = 0.f, s1 = 0.f, s2 = 0.f, s3 = 0.f, s4 = 0.f, s5 = 0.f, s6 = 0.f, s7 = 0.f;
#pragma unroll
    for (int c = 0; c < 9; ++c) {
        int r = rows[ln * 9 + c];
        f32x4 a = *(const f32x4*)&emb[r * 256 + c8];
        f32x4 b = *(const f32x4*)&emb[r * 256 + c8 + 4];
        s0 += a[0]; s1 += a[1]; s2 += a[2]; s3 += a[3];
        s4 += b[0]; s5 += b[1]; s6 += b[2]; s7 += b[3];
    }
    short8 o;
    o[0] = (short)f2h(s0); o[1] = (short)f2h(s1); o[2] = (short)f2h(s2); o[3] = (short)f2h(s3);
    o[4] = (short)f2h(s4); o[5] = (short)f2h(s5); o[6] = (short)f2h(s6); o[7] = (short)f2h(s7);
    *(short8*)&out[(size_t)(nb + ln) * 256 + c8] = o;
}

// ---------------- graph segment starts from sorted batch ----------------
__global__ void k_gstart(const int* __restrict__ batch, int* __restrict__ gstart, int N, int G) {
    int i = blockIdx.x * 256 + threadIdx.x;
    if (i >= N) return;
    int b = batch[i];
    if (i == 0) {
        for (int g = 0; g <= b; ++g) gstart[g] = 0;
    } else {
        int p = batch[i - 1];
        for (int g = p + 1; g <= b; ++g) gstart[g] = i;
    }
    if (i == N - 1) {
        for (int g = b + 1; g <= G; ++g) gstart[g] = N;
    }
}

// ---------------- CSR build (in-place in rp) ----------------
__global__ void k_count(const int* __restrict__ tgt, int* rp, int E) {
    int e = blockIdx.x * 256 + threadIdx.x;
    if (e < E) atomicAdd(&rp[tgt[e]], 1);
}

__global__ void k_dinv(const int* __restrict__ cnt, float* __restrict__ dinv, int N) {
    int i = blockIdx.x * 256 + threadIdx.x;
    if (i < N) dinv[i] = rsqrtf((float)cnt[i] + 1.f);
}

__global__ void k_scan1(int* __restrict__ rp, int* __restrict__ bsum, int N) {
    int t = threadIdx.x;
    int base = blockIdx.x * 1024 + t * 4;
    int v0 = 0, v1 = 0, v2 = 0, v3 = 0;
    if (base + 3 < N) {
        v0 = rp[base]; v1 = rp[base + 1]; v2 = rp[base + 2]; v3 = rp[base + 3];
    } else {
        if (base < N) v0 = rp[base];
        if (base + 1 < N) v1 = rp[base + 1];
        if (base + 2 < N) v2 = rp[base + 2];
    }
    int s = v0 + v1 + v2 + v3;
    int lane = t & 63, w = t >> 6;
    int x = s;
    for (int o = 1; o < 64; o <<= 1) {
        int y = __shfl_up(x, o, 64);
        if (lane >= o) x += y;
    }
    __shared__ int wsum[4];
    if (lane == 63) wsum[w] = x;
    __syncthreads();
    int woff = 0;
    for (int i = 0; i < w; ++i) woff += wsum[i];
    int excl = woff + x - s;
    if (base < N) rp[base] = excl;
    if (base + 1 < N) rp[base + 1] = excl + v0;
    if (base + 2 < N) rp[base + 2] = excl + v0 + v1;
    if (base + 3 < N) rp[base + 3] = excl + v0 + v1 + v2;
    if (t == 255) bsum[blockIdx.x] = wsum[0] + wsum[1] + wsum[2] + wsum[3];
}

__global__ void k_scan2(int* bsum, int nb) {
    int t = threadIdx.x;
    int s = (t < nb) ? bsum[t] : 0;
    int lane = t & 63, w = t >> 6;
    int x = s;
    for (int o = 1; o < 64; o <<= 1) {
        int y = __shfl_up(x, o, 64);
        if (lane >= o) x += y;
    }
    __shared__ int wsum[4];
    if (lane == 63) wsum[w] = x;
    __syncthreads();
    int woff = 0;
    for (int i = 0; i < w; ++i) woff += wsum[i];
    if (t < nb) bsum[t] = woff + x - s;
}

__global__ void k_scan3(int* __restrict__ rp, const int* __restrict__ bsum, int N) {
    int i = blockIdx.x * 256 + threadIdx.x;
    if (i < N) rp[i] += bsum[i >> 10];
}

// fill with packed (src, norm); afterwards rp[n] = end(n), start(n) = rp[n-1]
__global__ void k_fill(const int* __restrict__ src, const int* __restrict__ tgt,
                       int* __restrict__ rp, const float* __restrict__ dinv,
                       int2* __restrict__ est, int E) {
    int e = blockIdx.x * 256 + threadIdx.x;
    if (e < E) {
        int t = tgt[e];
        int s = src[e];
        int p = atomicAdd(&rp[t], 1);
        est[p] = make_int2(s, __float_as_int(dinv[s] * dinv[t]));
    }
}

// ---------------- GEMM: out[64 rows of X] <- A(from two half-buffers) @ Wp^T (+cvec) ----------------
__global__ __launch_bounds__(256, 3) void k_gemm(const u16* __restrict__ p0, int rs0,
                                                 const u16* __restrict__ p1, int rs1,
                                                 const u16* __restrict__ W,
                                                 const float* __restrict__ cvec,
                                                 u16* __restrict__ out, int N) {
    __shared__ u16 As[64][260];
    __shared__ u16 Ws[256][36];
    int r0 = blockIdx.x * 64;
    int tid = threadIdx.x, lane = tid & 63, w = tid >> 6;
#pragma unroll
    for (int i = 0; i < 8; ++i) {
        int chunk = i * 256 + tid;
        int r = chunk >> 5, c8 = chunk & 31;
        const u16* sp = (c8 < 16) ? &p0[(size_t)(r0 + r) * rs0 + c8 * 8]
                                  : &p1[(size_t)(r0 + r) * rs1 + (c8 - 16) * 8];
        *(short8*)&As[r][c8 * 8] = *(const short8*)sp;
    }
    f32x4 acc[16];
#pragma unroll
    for (int o = 0; o < 16; ++o) acc[o] = f32x4{0.f, 0.f, 0.f, 0.f};
    for (int k0 = 0; k0 < 256; k0 += 32) {
        __syncthreads();
#pragma unroll
        for (int i = 0; i < 4; ++i) {
            int chunk = i * 256 + tid;
            int r = chunk >> 2, c8 = chunk & 3;
            *(short8*)&Ws[r][c8 * 8] = *(const short8*)&W[(size_t)r * 256 + k0 + c8 * 8];
        }
        __syncthreads();
        half8 af = *(const half8*)&As[w * 16 + (lane & 15)][k0 + (lane >> 4) * 8];
#pragma unroll
        for (int o = 0; o < 16; ++o) {
            half8 wf = *(const half8*)&Ws[o * 16 + (lane & 15)][(lane >> 4) * 8];
            acc[o] = __builtin_amdgcn_mfma_f32_16x16x32_f16(af, wf, acc[o], 0, 0, 0);
        }
    }
    __syncthreads();
#pragma unroll
    for (int o = 0; o < 16; ++o) {
        int col = o * 16 + (lane & 15);
        float cv = cvec ? cvec[col] : 0.f;
#pragma unroll
        for (int r = 0; r < 4; ++r) {
            int row = w * 16 + (lane >> 4) * 4 + r;
            As[row][col] = f2h(acc[o][r] + cv);
        }
    }
    __syncthreads();
#pragma unroll
    for (int i = 0; i < 8; ++i) {
        int chunk = i * 256 + tid;
        int r = chunk >> 5, c8 = chunk & 31;
        *(short8*)&out[(size_t)(r0 + r) * 256 + c8 * 8] = *(const short8*)&As[r][c8 * 8];
    }
}

// ---------------- half aggregation: 16-lane sub-waves, CONTIGUOUS 4-node chunks ----------------
template <bool RS>
__global__ __launch_bounds__(256) void k_aggh(const u16* __restrict__ src, int srs,
                                              u16* __restrict__ dst, int drs,
                                              const int* __restrict__ rp,
                                              const int2* __restrict__ est,
                                              const float* __restrict__ dinv,
                                              const float* __restrict__ biasH,
                                              float* __restrict__ statS,
                                              float* __restrict__ statQ, int N) {
    int l = threadIdx.x & 15;
    int sub = blockIdx.x * 16 + (threadIdx.x >> 4);
    int n0 = sub * 4;
    if (n0 >= N) return;
    float bv[8];
#pragma unroll
    for (int k = 0; k < 8; ++k) bv[k] = biasH[l * 8 + k];
    float ss[8] = {}, qq[8] = {};
    int rA = n0 ? rp[n0 - 1] : 0;
#pragma unroll
    for (int t = 0; t < 4; ++t) {
        int n = n0 + t;
        int rB = rp[n];
        float dn = dinv[n];
        short8 hv = *(const short8*)&src[(size_t)n * srs + l * 8];
        float a[8];
#pragma unroll
        for (int k = 0; k < 8; ++k) a[k] = h2f((u16)hv[k]) * dn * dn + bv[k];
        int j = rA;
        for (; j + 1 < rB; j += 2) {
            int2 e0 = est[j], e1 = est[j + 1];
            float n0f = __int_as_float(e0.y), n1f = __int_as_float(e1.y);
            short8 v0 = *(const short8*)&src[(size_t)e0.x * srs + l * 8];
            short8 v1 = *(const short8*)&src[(size_t)e1.x * srs + l * 8];
#pragma unroll
            for (int k = 0; k < 8; ++k) a[k] += h2f((u16)v0[k]) * n0f + h2f((u16)v1[k]) * n1f;
        }
        if (j < rB) {
            int2 e0 = est[j];
            float n0f = __int_as_float(e0.y);
            short8 v0 = *(const short8*)&src[(size_t)e0.x * srs + l * 8];
#pragma unroll
            for (int k = 0; k < 8; ++k) a[k] += h2f((u16)v0[k]) * n0f;
        }
        rA = rB;
        short8 o;
#pragma unroll
        for (int k = 0; k < 8; ++k) {
            if (RS) {
                a[k] = fmaxf(a[k], 0.f);
                ss[k] += a[k];
                qq[k] += a[k] * a[k];
            }
            o[k] = (short)f2h(a[k]);
        }
        *(short8*)&dst[(size_t)n * drs + l * 8] = o;
    }
    if (RS) {
        __shared__ float sh[256];
        int t = threadIdx.x;
        sh[t] = 0.f;
        __syncthreads();
#pragma unroll
        for (int k = 0; k < 8; ++k) {
            atomicAdd(&sh[l * 8 + k], ss[k]);
            atomicAdd(&sh[128 + l * 8 + k], qq[k]);
        }
        __syncthreads();
        if (t < 128)
            atomicAdd(&statS[t], sh[t]);
        else
            atomicAdd(&statQ[t - 128], sh[t]);
    }
}

// ---------------- half snapshot copy (fallback tier) ----------------
__global__ void k_copyh(const u16* __restrict__ src, u16* __restrict__ dst, int N) {
    int i = blockIdx.x * 256 + threadIdx.x;
    if (i >= N * 16) return;
    int n = i >> 4, c8 = (i & 15) * 8;
    *(short8*)&dst[(size_t)n * 128 + c8] = *(const short8*)&src[(size_t)n * 256 + c8];
}

__global__ void k_bnparam(const float* __restrict__ stats, const float* __restrict__ gamma,
                          const float* __restrict__ beta, float* __restrict__ st, int N) {
    int d = threadIdx.x;
    float inv = 1.f / (float)N;
    float mu = stats[d] * inv;
    float var = fmaxf(stats[256 + d] * inv - mu * mu, 0.f);
    float sc = gamma[d] * rsqrtf(var + 1e-5f);
    st[d] = sc;
    st[256 + d] = beta[d] - mu * sc;
}

__global__ void k_fold(const float* __restrict__ W, const float* __restrict__ st,
                       u16* __restrict__ Wp, float* __restrict__ cvec) {
    __shared__ float red[256];
    int o = blockIdx.x, k = threadIdx.x;
    float w = W[o * 256 + k];
    Wp[o * 256 + k] = f2h(w * st[k]);
    red[k] = w * st[256 + k];
    __syncthreads();
    for (int s = 128; s > 0; s >>= 1) {
        if (k < s) red[k] += red[k + s];
        __syncthreads();
    }
    if (k == 0) cvec[o] = red[0];
}

// ---------------- set2set GEMM: C[M,O](f16) = A[M,K](f16) @ W[O,K](f16)^T + cvec ----------------
__global__ __launch_bounds__(256, 2) void k_gemmf(const u16* __restrict__ A,
                                                  const u16* __restrict__ W,
                                                  const float* __restrict__ cvec,
                                                  u16* __restrict__ C, int M, int K, int O) {
    const int PAD = 8;
    __shared__ u16 As[128][64 + PAD];
    __shared__ u16 Ws[128][64 + PAD];
    int tM = blockIdx.x, tO = blockIdx.y;
    int tid = threadIdx.x;
    int lane = tid & 63, wid = tid >> 6;
    int wM = wid & 1, wO = wid >> 1;
    f32x4 acc[4][4] = {};
    size_t rowA0 = (size_t)tM * 128, rowW0 = (size_t)tO * 128;
    for (int k0 = 0; k0 < K; k0 += 64) {
#pragma unroll
        for (int i = 0; i < 4; ++i) {
            int chunk = tid + i * 256;
            int r = chunk >> 3, c16 = chunk & 7;
            *(short8*)&As[r][c16 * 8] = *(const short8*)&A[(rowA0 + r) * K + k0 + c16 * 8];
            *(short8*)&Ws[r][c16 * 8] = *(const short8*)&W[(rowW0 + r) * K + k0 + c16 * 8];
        }
        __syncthreads();
#pragma unroll
        for (int ks = 0; ks < 2; ++ks) {
            half8 af[4], wf[4];
#pragma unroll
            for (int m = 0; m < 4; ++m)
                af[m] = *(const half8*)&As[wM * 64 + m * 16 + (lane & 15)][ks * 32 + (lane >> 4) * 8];
#pragma unroll
            for (int o = 0; o < 4; ++o)
                wf[o] = *(const half8*)&Ws[wO * 64 + o * 16 + (lane & 15)][ks * 32 + (lane >> 4) * 8];
#pragma unroll
            for (int m = 0; m < 4; ++m)
#pragma unroll
                for (int o = 0; o < 4; ++o)
                    acc[m][o] = __builtin_amdgcn_mfma_f32_16x16x32_f16(af[m], wf[o], acc[m][o], 0, 0, 0);
        }
        __syncthreads();
    }
#pragma unroll
    for (int m = 0; m < 4; ++m) {
        int R0 = tM * 128 + wM * 64 + m * 16 + (lane >> 4) * 4;
#pragma unroll
        for (int o = 0; o < 4; ++o) {
            int Cc = tO * 128 + wO * 64 + o * 16 + (lane & 15);
            float cv = cvec[Cc];
#pragma unroll
            for (int r = 0; r < 4; ++r)
                C[(size_t)(R0 + r) * O + Cc] = f2h(acc[m][o][r] + cv);
        }
    }
}

// ---------------- set2set pieces ----------------
__global__ void k_wcat(const float* __restrict__ Wi, const float* __restrict__ Wh,
                       const float* __restrict__ bi, const float* __restrict__ bh,
                       u16* __restrict__ Wcat, float* __restrict__ bcat) {
    int o = blockIdx.x;
    int t = threadIdx.x;
    for (int c = t; c < 512; c += 256) Wcat[(size_t)o * 768 + c] = f2h(Wi[(size_t)o * 512 + c]);
    if (t < 256) Wcat[(size_t)o * 768 + 512 + t] = f2h(Wh[(size_t)o * 256 + t]);
    if (t == 0) bcat[o] = bi[o] + bh[o];
}

__global__ void k_lstm(const u16* __restrict__ gates, float* __restrict__ cs,
                       float* __restrict__ hsb, u16* __restrict__ qsh, int G) {
    int idx = blockIdx.x * 256 + threadIdx.x;
    if (idx >= G * 256) return;
    int g = idx >> 8, d = idx & 255;
    const u16* gt = &gates[(size_t)g * 1024];
    float gi = h2f(gt[d]), gf = h2f(gt[256 + d]), gg = h2f(gt[512 + d]), go = h2f(gt[768 + d]);
    float c = sigf(gf) * cs[idx] + sigf(gi) * tanhf(gg);
    float hh = sigf(go) * tanhf(c);
    cs[idx] = c;
    hsb[idx] = hh;
    u16 hb = f2h(hh);
    qsh[(size_t)g * 768 + d] = hb;
    qsh[(size_t)g * 768 + 512 + d] = hb;
}

// ---------------- attention: one wave per graph; h3 may be split across two buffers ----------------
__global__ __launch_bounds__(256) void k_attn2(const u16* __restrict__ lo, int lstr,
                                               const u16* __restrict__ hi, int hstr,
                                               const float* __restrict__ hs,
                                               const int* __restrict__ gstart,
                                               u16* __restrict__ qsh, int G) {
    int wid = threadIdx.x >> 6, lane = threadIdx.x & 63;
    int g = blockIdx.x * 4 + wid;
    if (g >= G) return;
    int start = gstart[g], end = gstart[g + 1];

    const u16* base = (lane < 32) ? lo : hi;
    size_t stride = (lane < 32) ? lstr : hstr;
    int coff = (lane < 32) ? lane * 4 : (lane - 32) * 4;

    f32x4 q = *(const f32x4*)&hs[(size_t)g * 256 + lane * 4];
    float m = -INFINITY, z = 0.f;
    float r0a = 0.f, r1a = 0.f, r2a = 0.f, r3a = 0.f;

    for (int c0 = start; c0 < end; c0 += 256) {
        int cn = min(256, end - c0);
        float e0 = 0.f, e1 = 0.f, e2 = 0.f, e3 = 0.f;
        float mc = m;

        auto pass1 = [&](int rr, float& ev) {
            int b = c0 + rr * 64;
            int nr = min(64, end - b);
            for (int ii = 0; ii < nr; ++ii) {
                u16x4 hv = *(const u16x4*)&base[(size_t)(b + ii) * stride + coff];
                float e = h2f(hv[0]) * q[0] + h2f(hv[1]) * q[1] + h2f(hv[2]) * q[2] + h2f(hv[3]) * q[3];
                e += __shfl_xor(e, 32, 64);
                e += __shfl_xor(e, 16, 64);
                e += __shfl_xor(e, 8, 64);
                e += __shfl_xor(e, 4, 64);
                e += __shfl_xor(e, 2, 64);
                e += __shfl_xor(e, 1, 64);
                if (lane == ii) ev = e;
                mc = fmaxf(mc, e);
            }
        };
        pass1(0, e0);
        pass1(1, e1);
        pass1(2, e2);
        pass1(3, e3);

        float rf = (m == -INFINITY) ? 0.f : expf(m - mc);
        float zc = 0.f;
        e0 = (lane < cn) ? expf(e0 - mc) : 0.f;
        zc += e0;
        e1 = (64 + lane < cn) ? expf(e1 - mc) : 0.f;
        zc += e1;
        e2 = (128 + lane < cn) ? expf(e2 - mc) : 0.f;
        zc += e2;
        e3 = (192 + lane < cn) ? expf(e3 - mc) : 0.f;
        zc += e3;
        zc += __shfl_xor(zc, 32, 64);
        zc += __shfl_xor(zc, 16, 64);
        zc += __shfl_xor(zc, 8, 64);
        zc += __shfl_xor(zc, 4, 64);
        zc += __shfl_xor(zc, 2, 64);
        zc += __shfl_xor(zc, 1, 64);
        z = z * rf + zc;
        r0a *= rf; r1a *= rf; r2a *= rf; r3a *= rf;

        auto pass2 = [&](int rr, float ev) {
            int b = c0 + rr * 64;
            int nr = min(64, end - b);
            for (int ii = 0; ii < nr; ++ii) {
                float w = __shfl(ev, ii, 64);
                u16x4 hv = *(const u16x4*)&base[(size_t)(b + ii) * stride + coff];
                r0a += w * h2f(hv[0]);
                r1a += w * h2f(hv[1]);
                r2a += w * h2f(hv[2]);
                r3a += w * h2f(hv[3]);
            }
        };
        pass2(0, e0);
        pass2(1, e1);
        pass2(2, e2);
        pass2(3, e3);
        m = mc;
    }
    float inv = (end > start) ? 1.f / fmaxf(z, 1e-30f) : 0.f;
    u16x4 o;
    o[0] = f2h(r0a * inv);
    o[1] = f2h(r1a * inv);
    o[2] = f2h(r2a * inv);
    o[3] = f2h(r3a * inv);
    // lane<32 owns cols lane*4 (from lo), lane>=32 owns 128+(lane-32)*4 (from hi)
    int qcol = (lane < 32) ? lane * 4 : 128 + (lane - 32) * 4;
    *(u16x4*)&qsh[(size_t)g * 768 + 256 + qcol] = o;
}

// lin1/lin2 compose
__global__ void k_wfold(const float* __restrict__ l1W, const float* __restrict__ l1b,
                        const float* __restrict__ l2W, const float* __restrict__ l2b,
                        float* __restrict__ weff) {
    int c = blockIdx.x * 256 + threadIdx.x;
    if (c < 512) {
        float s = 0.f;
        for (int t = 0; t < 128; ++t) s += l2W[t] * l1W[(size_t)t * 512 + c];
        weff[c] = s;
    }
    if (c == 0) {
        float b = l2b[0];
        for (int t = 0; t < 128; ++t) b += l2W[t] * l1b[t];
        weff[512] = b;
    }
}

__global__ __launch_bounds__(256) void k_final2(const u16* __restrict__ qsh,
                                                const float* __restrict__ weff,
                                                float* __restrict__ out, int G) {
    __shared__ float wsm[513];
    int tid = threadIdx.x;
    for (int j = tid; j < 513; j += 256) wsm[j] = weff[j];
    __syncthreads();
    int g = blockIdx.x * 4 + (tid >> 6);
    int lane = tid & 63;
    if (g >= G) return;
    const u16* qp = &qsh[(size_t)g * 768];
    float s = 0.f;
#pragma unroll
    for (int j = 0; j < 8; ++j) s += h2f(qp[lane * 8 + j]) * wsm[lane * 8 + j];
    for (int off = 32; off; off >>= 1) s += __shfl_xor(s, off, 64);
    if (lane == 0) out[g] = sigf(s + wsm[512]);
}

// ---------------- host ----------------
extern "C" void kernel_launch(void* const* d_in, const int* in_sizes, int n_in,
                              void* d_out, int out_size, void* d_ws, size_t ws_size,
                              hipStream_t stream) {
    const int* x = (const int*)d_in[0];
    const int* ei = (const int*)d_in[1];
    const int* batch = (const int*)d_in[2];
    const float* atom_emb = (const float*)d_in[4];
    const float* W1 = (const float*)d_in[5];
    const float* b1 = (const float*)d_in[6];
    const float* W2 = (const float*)d_in[7];
    const float* b2 = (const float*)d_in[8];
    const float* W3 = (const float*)d_in[9];
    const float* b3 = (const float*)d_in[10];
    const float* gamma = (const float*)d_in[11];
    const float* beta = (const float*)d_in[12];
    const float* Wi = (const float*)d_in[13];
    const float* Wh = (const float*)d_in[14];
    const float* bi = (const float*)d_in[15];
    const float* bh = (const float*)d_in[16];
    const float* l1W = (const float*)d_in[17];
    const float* l1b = (const float*)d_in[18];
    const float* l2W = (const float*)d_in[19];
    const float* l2b = (const float*)d_in[20];

    const int N = in_sizes[0] / 9;
    const int E = in_sizes[1] / 2;
    const int G = out_size;
    const int* srcp = ei;
    const int* tgtp = ei + E;

    char* ws = (char*)d_ws;
    size_t off = 0;
    auto alloc = [&](size_t bytes) -> void* {
        void* p = ws + off;
        off += (bytes + 255) & ~(size_t)255;
        return p;
    };
    u16* X = (u16*)alloc((size_t)N * 256 * 2);  // 128 MiB
    int* rp = (int*)alloc((size_t)N * 4);
    int2* est = (int2*)alloc((size_t)E * 8);
    float* dinv = (float*)alloc((size_t)N * 4);
    int* gstart = (int*)alloc((size_t)(G + 1) * 4);
    float* stats = (float*)alloc(512 * 4);
    float* stbuf = (float*)alloc(512 * 4);
    float* cvec = (float*)alloc(256 * 4);
    u16* Wp = (u16*)alloc(256 * 256 * 2);
    int* bsum = (int*)alloc(1024 * 4);
    float* weff = (float*)alloc(513 * 4);
    size_t offR = off;

    size_t halfB = ((size_t)N * 128 * 2 + 255) & ~(size_t)255;  // 64 MiB
    // s2s sizing
    size_t s2sR = 0;
    {
        size_t t = 0;
        auto sz = [&](size_t b) { t += (b + 255) & ~(size_t)255; };
        sz((size_t)1024 * 768 * 2);  // Wcat
        sz(1024 * 4);                // bcat
        sz((size_t)G * 768 * 2);     // qsh
        sz((size_t)G * 1024 * 2);    // gates
        sz((size_t)G * 256 * 4);     // hsb
        sz((size_t)G * 256 * 4);     // csb
        s2sR = t;
    }
    size_t needA = offR + halfB + s2sR;                          // Y live through s2s
    size_t needB = offR + (halfB > s2sR ? halfB : s2sR);         // s2s aliases Y
    bool tierA = ws_size >= needA;
    if (!tierA && ws_size < needB) {
        k_diagf<<<(G + 255) / 256, 256, 0, stream>>>((float*)d_out, G, 12345.0f);
        return;
    }
    u16* Y = (u16*)(ws + offR);
    size_t s2sBase = tierA ? offR + halfB : offR;
    size_t o2 = s2sBase;
    auto alloc2 = [&](size_t bytes) -> void* {
        void* p = ws + o2;
        o2 += (bytes + 255) & ~(size_t)255;
        return p;
    };
    u16* Wcat = (u16*)alloc2((size_t)1024 * 768 * 2);
    float* bcat = (float*)alloc2(1024 * 4);
    u16* qsh = (u16*)alloc2((size_t)G * 768 * 2);
    u16* gates = (u16*)alloc2((size_t)G * 1024 * 2);
    float* hsb = (float*)alloc2((size_t)G * 256 * 4);
    float* csb = (float*)alloc2((size_t)G * 256 * 4);

    // embed + segment starts + CSR
    k_embed<<<N / 8, 256, 0, stream>>>(x, atom_emb, X, N);
    k_gstart<<<(N + 255) / 256, 256, 0, stream>>>(batch, gstart, N, G);
    k_zero_int<<<(N + 255) / 256, 256, 0, stream>>>(rp, N);
    k_count<<<(E + 255) / 256, 256, 0, stream>>>(tgtp, rp, E);
    k_dinv<<<(N + 255) / 256, 256, 0, stream>>>(rp, dinv, N);
    int nb1 = (N + 1023) / 1024;
    k_scan1<<<nb1, 256, 0, stream>>>(rp, bsum, N);
    k_scan2<<<1, 256, 0, stream>>>(bsum, nb1);
    k_scan3<<<(N + 255) / 256, 256, 0, stream>>>(rp, bsum, N);
    k_fill<<<(E + 255) / 256, 256, 0, stream>>>(srcp, tgtp, rp, dinv, est, E);

    int gipb = N / 64;
    int cpb = (N * 16 + 255) / 256;
    int aggb = (N / 4 + 15) / 16;  // contiguous 4-node chunks, exact cover

    // conv1: GEMM X->X; agg h0: X+0 -> Y; agg h1: X+128 -> X+0. State: (Y/128, X+0/256).
    k_cvtW<<<256, 256, 0, stream>>>(W1, Wp, 65536);
    k_zero_f32<<<2, 256, 0, stream>>>(stats, 512);
    k_gemm<<<gipb, 256, 0, stream>>>(X, 256, X + 128, 256, Wp, nullptr, X, N);
    k_aggh<true><<<aggb, 256, 0, stream>>>(X, 256, Y, 128, rp, est, dinv, b1, stats, stats + 256, N);
    k_aggh<true><<<aggb, 256, 0, stream>>>(X + 128, 256, X, 256, rp, est, dinv, b1 + 128, stats + 128, stats + 384, N);
    k_bnparam<<<1, 256, 0, stream>>>(stats, gamma, beta, stbuf, N);

    // conv2
    k_fold<<<256, 256, 0, stream>>>(W2, stbuf, Wp, cvec);
    k_zero_f32<<<2, 256, 0, stream>>>(stats, 512);
    k_gemm<<<gipb, 256, 0, stream>>>(Y, 128, X, 256, Wp, cvec, X, N);
    k_aggh<true><<<aggb, 256, 0, stream>>>(X, 256, Y, 128, rp, est, dinv, b2, stats, stats + 256, N);
    k_aggh<true><<<aggb, 256, 0, stream>>>(X + 128, 256, X, 256, rp, est, dinv, b2 + 128, stats + 128, stats + 384, N);
    k_bnparam<<<1, 256, 0, stream>>>(stats, gamma, beta, stbuf, N);

    // conv3
    k_fold<<<256, 256, 0, stream>>>(W3, stbuf, Wp, cvec);
    k_gemm<<<gipb, 256, 0, stream>>>(Y, 128, X, 256, Wp, cvec, X, N);
    const u16 *h3lo, *h3hi;
    int h3ls, h3hs;
    if (tierA) {
        // rotation, no copies; h3 lo in Y, hi in X+0; Y stays live through s2s
        k_aggh<false><<<aggb, 256, 0, stream>>>(X, 256, Y, 128, rp, est, dinv, b3, nullptr, nullptr, N);
        k_aggh<false><<<aggb, 256, 0, stream>>>(X + 128, 256, X, 256, rp, est, dinv, b3 + 128, nullptr, nullptr, N);
        h3lo = Y; h3ls = 128; h3hi = X; h3hs = 256;
    } else {
        // copy path; h3 fully in X; Y freed for s2s alias
        k_copyh<<<cpb, 256, 0, stream>>>(X, Y, N);
        k_aggh<false><<<aggb, 256, 0, stream>>>(Y, 128, X, 256, rp, est, dinv, b3, nullptr, nullptr, N);
        k_copyh<<<cpb, 256, 0, stream>>>(X + 128, Y, N);
        k_aggh<false><<<aggb, 256, 0, stream>>>(Y, 128, X + 128, 256, rp, est, dinv, b3 + 128, nullptr, nullptr, N);
        h3lo = X; h3ls = 256; h3hi = X + 128; h3hs = 256;
    }

    // set2set
    k_wcat<<<1024, 256, 0, stream>>>(Wi, Wh, bi, bh, Wcat, bcat);
    k_zero_u16<<<(G * 768 + 255) / 256, 256, 0, stream>>>(qsh, G * 768);
    k_zero_f32<<<(G * 256 + 255) / 256, 256, 0, stream>>>(csb, G * 256);
    dim3 ggates(G / 128, 8);
    for (int s = 0; s < 4; ++s) {
        k_gemmf<<<ggates, 256, 0, stream>>>(qsh, Wcat, bcat, gates, G, 768, 1024);
        k_lstm<<<(G * 256 + 255) / 256, 256, 0, stream>>>(gates, csb, hsb, qsh, G);
        k_attn2<<<(G + 3) / 4, 256, 0, stream>>>(h3lo, h3ls, h3hi, h3hs, hsb, gstart, qsh, G);
    }
    k_wfold<<<2, 256, 0, stream>>>(l1W, l1b, l2W, l2b, weff);
    k_final2<<<(G + 3) / 4, 256, 0, stream>>>(qsh, weff, (float*)d_out, G);
}